// Round 5
// baseline (797.548 us; speedup 1.0000x reference)
//
#include <hip/hip_runtime.h>

#define NNODE 16384
#define NEDGE 32768
#define NG    256
#define TPGx  12
#define TTOT  (NG * TPGx)   // 3072
#define D     64
#define KTOT  4160          // 64*64 + 64 bias tail

typedef __bf16 b8 __attribute__((ext_vector_type(8)));
typedef float  f4 __attribute__((ext_vector_type(4)));

static __device__ __forceinline__ float sigm(float x) { return 1.f / (1.f + __expf(-x)); }

static __device__ __forceinline__ f4 mfma16(b8 a, b8 b, f4 c) {
  return __builtin_amdgcn_mfma_f32_16x16x32_bf16(a, b, c, 0, 0, 0);
}

// ---------------- workspace layout (byte offsets) ----------------
#define WS_H      0          // float [N*64]   4 MiB
#define WS_AGG    4194304    // float [N*64]   4 MiB
#define WS_W2HI   8388608    // bf16  [64*KTOT] row o: [i*64+k], tail [4096+i]
#define WS_W2LO   8921088    // bf16  [64*KTOT]
#define WS_RTHI   9453568    // bf16  [64*64]  rt[o][i]
#define WS_RTLO   9461760
#define WS_WHHHI  9469952    // bf16  [192*64] natural [oo][i]
#define WS_WHHLO  9494528
#define WS_WIHHI  9519104    // bf16  [192*64]
#define WS_WIHLO  9543680
#define WS_SWIH   9568256    // f32   [256*128]
#define WS_SWHH   9699328    // f32   [256*64]
#define WS_MWIH   9764864    // f32   [256*128]
#define WS_L1WF   9895936    // f32   [64*320]
#define WS_L2WF   9977856    // f32   [6*64]
#define WS_FB     9979392    // f32   [2246]
#define WS_DEG    9988608    // f32   [N]
#define WS_HX     10054144   // f32   [G*64]
#define WS_NEED   10119680
// fb sub-offsets (floats): lin0w 0, lin0b 192, e1w 256, e1b 640, convb 704,
// gbih 768, gbhh 960, s2sbih 1152, s2sbhh 1408, membih 1664, membhh 1920,
// l1b 2176, l2b 2240

// ---------------- pack fp32 params; split GEMM weights into bf16 hi+lo ----------------
struct Srcs { const void* p[23]; };

__device__ __constant__ const int kCum[24] = {
    0, 192, 256, 640, 704, 262848, 266944, 271040, 271104, 283392, 295680,
    295872, 296064, 328832, 345216, 345472, 345728, 378496, 378752, 379008,
    399488, 399552, 399936, 399942};

__global__ __launch_bounds__(256) void pack_kernel(Srcs S, char* __restrict__ ws) {
  int idx = blockIdx.x * 256 + threadIdx.x;
  if (idx >= 399942) return;
  int r = 0, base = 0;
#pragma unroll
  for (int k = 0; k < 23; k++)
    if (idx >= kCum[k]) { r = k; base = kCum[k]; }
  int li = idx - base;
  float v = ((const float*)S.p[r])[li];
  __bf16 hi = (__bf16)v;
  __bf16 lo = (__bf16)(v - (float)hi);

  float*  fb    = (float*)(ws + WS_FB);
  __bf16* w2hi  = (__bf16*)(ws + WS_W2HI);
  __bf16* w2lo  = (__bf16*)(ws + WS_W2LO);
  __bf16* rtHi  = (__bf16*)(ws + WS_RTHI);
  __bf16* rtLo  = (__bf16*)(ws + WS_RTLO);
  __bf16* whhHi = (__bf16*)(ws + WS_WHHHI);
  __bf16* whhLo = (__bf16*)(ws + WS_WHHLO);
  __bf16* wihHi = (__bf16*)(ws + WS_WIHHI);
  __bf16* wihLo = (__bf16*)(ws + WS_WIHLO);
  float*  swih  = (float*)(ws + WS_SWIH);
  float*  swhh  = (float*)(ws + WS_SWHH);
  float*  mwih  = (float*)(ws + WS_MWIH);
  float*  l1w   = (float*)(ws + WS_L1WF);
  float*  l2w   = (float*)(ws + WS_L2WF);

  switch (r) {
    case 0: fb[li] = v; break;          // lin0_w
    case 1: fb[192 + li] = v; break;    // lin0_b
    case 2: fb[256 + li] = v; break;    // e1_w
    case 3: fb[640 + li] = v; break;    // e1_b
    case 4: {                           // e2_w flat (i*64+o)*64+k -> [o][i*64+k]
      int i = li >> 12, o = (li >> 6) & 63, k = li & 63;
      int off = o * KTOT + i * 64 + k;
      w2hi[off] = hi; w2lo[off] = lo;
    } break;
    case 5: {                           // e2_b flat i*64+o -> [o][4096+i]
      int i = li >> 6, o = li & 63;
      int off = o * KTOT + 4096 + i;
      w2hi[off] = hi; w2lo[off] = lo;
    } break;
    case 6: {                           // root_w [i][o] -> rt[o*64+i]
      int i = li >> 6, o = li & 63;
      rtHi[o * 64 + i] = hi; rtLo[o * 64 + i] = lo;
    } break;
    case 7: fb[704 + li] = v; break;    // conv_b
    case 8: wihHi[li] = hi; wihLo[li] = lo; break;   // gru_wih [oo][i]
    case 9: whhHi[li] = hi; whhLo[li] = lo; break;   // gru_whh [oo][i]
    case 10: fb[768 + li] = v; break;   // gru_bih
    case 11: fb[960 + li] = v; break;   // gru_bhh
    case 12: swih[li] = v; break;
    case 13: swhh[li] = v; break;
    case 14: fb[1152 + li] = v; break;  // s2s_bih
    case 15: fb[1408 + li] = v; break;  // s2s_bhh
    case 16: mwih[li] = v; break;
    case 17: fb[1664 + li] = v; break;  // mem_bih
    case 18: fb[1920 + li] = v; break;  // mem_bhh
    case 19: l1w[li] = v; break;
    case 20: fb[2176 + li] = v; break;  // lin1_b
    case 21: l2w[li] = v; break;
    case 22: fb[2240 + li] = v; break;  // lin2_b
  }
}

// ---------------- node init: h = relu(x @ lin0_w.T + lin0_b), fp32 ----------------
__global__ __launch_bounds__(256) void init_kernel(
    const float* __restrict__ x, const float* __restrict__ fb,
    float* __restrict__ h) {
  int idx = blockIdx.x * 256 + threadIdx.x;  // n*64+o
  int n = idx >> 6, o = idx & 63;
  float acc = fb[192 + o];
#pragma unroll
  for (int j = 0; j < 3; j++) acc += x[n * 3 + j] * fb[o * 3 + j];
  h[idx] = fmaxf(acc, 0.f);
}

// ---------------- degree ----------------
__global__ __launch_bounds__(256) void deg_kernel(const int* __restrict__ edge_index,
                                                  float* __restrict__ deg) {
  int e = blockIdx.x * 256 + threadIdx.x;
  if (e < NEDGE) atomicAdd(&deg[edge_index[NEDGE + e]], 1.0f);
}

// ---------------- message GEMM, split-bf16: msg = z @ W2 (z fp32-built on the fly) ----
// 512 threads = 8 waves; 128 edges/block; per-i B-tile staged in LDS.
__global__ __launch_bounds__(512) void msg_kernel(
    const float* __restrict__ h, const float* __restrict__ ea,
    const float* __restrict__ fb,
    const __bf16* __restrict__ w2hi, const __bf16* __restrict__ w2lo,
    const int* __restrict__ edge_index, float* __restrict__ agg) {
  __shared__ float  sOut[128][68];
  __shared__ __bf16 sBh[64][72];
  __shared__ __bf16 sBl[64][72];
  const int tid = threadIdx.x;
  const int wave = tid >> 6, lane = tid & 63;
  const int m15 = lane & 15, quad = lane >> 4;
  const int eb = blockIdx.x * 128;
  {  // stage out[src] fp32 for 128 edges
    int r = tid >> 2, c0 = (tid & 3) * 16;
    int srcn = edge_index[eb + r];
#pragma unroll
    for (int c = c0; c < c0 + 16; c += 4)
      *(float4*)&sOut[r][c] = *(const float4*)&h[srcn * D + c];
  }
  const int erow = wave * 16 + m15;
  const int e = eb + erow;
  // recompute edge hidden in fp32 for this lane's k-slices
  float hid0[8], hid1[8];
  {
    float eav[6];
#pragma unroll
    for (int j = 0; j < 6; j++) eav[j] = ea[e * 6 + j];
#pragma unroll
    for (int j = 0; j < 8; j++) {
      int k0 = quad * 8 + j, k1 = 32 + quad * 8 + j;
      float a0 = fb[640 + k0], a1 = fb[640 + k1];
#pragma unroll
      for (int jj = 0; jj < 6; jj++) {
        a0 += eav[jj] * fb[256 + k0 * 6 + jj];
        a1 += eav[jj] * fb[256 + k1 * 6 + jj];
      }
      hid0[j] = fmaxf(a0, 0.f);
      hid1[j] = fmaxf(a1, 0.f);
    }
  }
  f4 zz = {0.f, 0.f, 0.f, 0.f};
  f4 acc0 = zz, acc1 = zz, acc2 = zz, acc3 = zz;
  const int bo = tid >> 3, bk = (tid & 7) * 8;  // B staging coords
  for (int i = 0; i < 65; i++) {
    {  // stage B tile i (hi+lo): sB[o][k] = W2[i*64+k][o]
      int off = bo * KTOT + i * 64 + bk;
      *(b8*)&sBh[bo][bk] = *(const b8*)(w2hi + off);
      *(b8*)&sBl[bo][bk] = *(const b8*)(w2lo + off);
    }
    __syncthreads();
    // build A fragments (fp32 z -> hi/lo split)
    float zs0[8], zs1[8];
    if (i < 64) {
      float os = sOut[erow][i];
#pragma unroll
      for (int j = 0; j < 8; j++) { zs0[j] = os * hid0[j]; zs1[j] = os * hid1[j]; }
    } else {  // bias tail: z = out_src
#pragma unroll
      for (int j = 0; j < 8; j++) {
        zs0[j] = sOut[erow][quad * 8 + j];
        zs1[j] = sOut[erow][32 + quad * 8 + j];
      }
    }
    b8 a0h, a0l, a1h, a1l;
#pragma unroll
    for (int j = 0; j < 8; j++) {
      __bf16 h0 = (__bf16)zs0[j]; a0h[j] = h0; a0l[j] = (__bf16)(zs0[j] - (float)h0);
      __bf16 h1 = (__bf16)zs1[j]; a1h[j] = h1; a1l[j] = (__bf16)(zs1[j] - (float)h1);
    }
#pragma unroll
    for (int nt = 0; nt < 4; nt++) {
      int br = nt * 16 + m15;
      b8 bh0 = *(const b8*)&sBh[br][quad * 8];
      b8 bl0 = *(const b8*)&sBl[br][quad * 8];
      b8 bh1 = *(const b8*)&sBh[br][32 + quad * 8];
      b8 bl1 = *(const b8*)&sBl[br][32 + quad * 8];
      f4 a = (nt == 0) ? acc0 : (nt == 1) ? acc1 : (nt == 2) ? acc2 : acc3;
      a = mfma16(a0h, bh0, a);
      a = mfma16(a0l, bh0, a);
      a = mfma16(a0h, bl0, a);
      a = mfma16(a1h, bh1, a);
      a = mfma16(a1l, bh1, a);
      a = mfma16(a1h, bl1, a);
      if (nt == 0) acc0 = a; else if (nt == 1) acc1 = a; else if (nt == 2) acc2 = a; else acc3 = a;
    }
    __syncthreads();
  }
#pragma unroll
  for (int reg = 0; reg < 4; reg++) {
    int ee = eb + wave * 16 + quad * 4 + reg;
    int dn = edge_index[NEDGE + ee];
    float* ap = agg + dn * D;
    atomicAdd(ap + m15,      acc0[reg]);
    atomicAdd(ap + 16 + m15, acc1[reg]);
    atomicAdd(ap + 32 + m15, acc2[reg]);
    atomicAdd(ap + 48 + m15, acc3[reg]);
  }
}

// ---------------- node update, split-bf16 MFMA; gh kept in registers ----------------
__global__ __launch_bounds__(256) void update_kernel(
    float* __restrict__ h, const float* __restrict__ agg, const float* __restrict__ deg,
    const __bf16* __restrict__ rtHi, const __bf16* __restrict__ rtLo,
    const __bf16* __restrict__ whhHi, const __bf16* __restrict__ whhLo,
    const __bf16* __restrict__ wihHi, const __bf16* __restrict__ wihLo,
    const float* __restrict__ fb) {
  __shared__ float buf[64][68];  // sH, then (after barrier) sM
  const int tid = threadIdx.x;
  const int wave = tid >> 6, lane = tid & 63;
  const int m15 = lane & 15, quad = lane >> 4;
  const int nb = blockIdx.x * 64;
  {
    int r = tid >> 2, c0 = (tid & 3) * 16;
#pragma unroll
    for (int c = c0; c < c0 + 16; c += 4)
      *(float4*)&buf[r][c] = *(const float4*)&h[(nb + r) * D + c];
  }
  __syncthreads();
  const int mrow = wave * 16 + m15;
  b8 a0h, a0l, a1h, a1l;
#pragma unroll
  for (int j = 0; j < 8; j++) {
    float v0 = buf[mrow][quad * 8 + j];
    float v1 = buf[mrow][32 + quad * 8 + j];
    __bf16 h0 = (__bf16)v0; a0h[j] = h0; a0l[j] = (__bf16)(v0 - (float)h0);
    __bf16 h1 = (__bf16)v1; a1h[j] = h1; a1l[j] = (__bf16)(v1 - (float)h1);
  }
  f4 zz = {0.f, 0.f, 0.f, 0.f};
  f4 acc[16];
#pragma unroll
  for (int nt = 0; nt < 16; nt++) acc[nt] = zz;
#pragma unroll
  for (int nt = 0; nt < 16; nt++) {
    int nn = nt * 16 + m15;
    const __bf16* bh = (nt < 4) ? (rtHi + nn * D) : (whhHi + (nn - 64) * D);
    const __bf16* bl = (nt < 4) ? (rtLo + nn * D) : (whhLo + (nn - 64) * D);
    b8 bh0 = *(const b8*)(bh + quad * 8);
    b8 bl0 = *(const b8*)(bl + quad * 8);
    b8 bh1 = *(const b8*)(bh + 32 + quad * 8);
    b8 bl1 = *(const b8*)(bl + 32 + quad * 8);
    f4 a = acc[nt];
    a = mfma16(a0h, bh0, a);
    a = mfma16(a0l, bh0, a);
    a = mfma16(a0h, bl0, a);
    a = mfma16(a1h, bh1, a);
    a = mfma16(a1l, bh1, a);
    a = mfma16(a1h, bl1, a);
    acc[nt] = a;
  }
  __syncthreads();  // everyone done reading sH
  // m = relu(root + agg/deg + conv_b), fp32, into buf (C-layout -> rows)
#pragma unroll
  for (int nt = 0; nt < 4; nt++) {
#pragma unroll
    for (int reg = 0; reg < 4; reg++) {
      int nloc = wave * 16 + quad * 4 + reg;
      int o = nt * 16 + m15;
      float dg = fmaxf(deg[nb + nloc], 1.f);
      float v = acc[nt][reg] + agg[(nb + nloc) * D + o] / dg + fb[704 + o];
      buf[nloc][o] = fmaxf(v, 0.f);
    }
  }
  __syncthreads();
  b8 m0h, m0l, m1h, m1l;
#pragma unroll
  for (int j = 0; j < 8; j++) {
    float v0 = buf[mrow][quad * 8 + j];
    float v1 = buf[mrow][32 + quad * 8 + j];
    __bf16 h0 = (__bf16)v0; m0h[j] = h0; m0l[j] = (__bf16)(v0 - (float)h0);
    __bf16 h1 = (__bf16)v1; m1h[j] = h1; m1l[j] = (__bf16)(v1 - (float)h1);
  }
  f4 g2[12];
#pragma unroll
  for (int nt = 0; nt < 12; nt++) g2[nt] = zz;
#pragma unroll
  for (int nt = 0; nt < 12; nt++) {
    int nn = nt * 16 + m15;
    const __bf16* bh = wihHi + nn * D;
    const __bf16* bl = wihLo + nn * D;
    b8 bh0 = *(const b8*)(bh + quad * 8);
    b8 bl0 = *(const b8*)(bl + quad * 8);
    b8 bh1 = *(const b8*)(bh + 32 + quad * 8);
    b8 bl1 = *(const b8*)(bl + 32 + quad * 8);
    f4 a = g2[nt];
    a = mfma16(m0h, bh0, a);
    a = mfma16(m0l, bh0, a);
    a = mfma16(m0h, bl0, a);
    a = mfma16(m1h, bh1, a);
    a = mfma16(m1l, bh1, a);
    a = mfma16(m1h, bl1, a);
    g2[nt] = a;
  }
#pragma unroll
  for (int nt = 0; nt < 4; nt++) {
#pragma unroll
    for (int reg = 0; reg < 4; reg++) {
      int nloc = wave * 16 + quad * 4 + reg;
      int o = nt * 16 + m15;
      int gidx = (nb + nloc) * D + o;
      float gir = g2[nt][reg]      + fb[768 + o];
      float giz = g2[nt + 4][reg]  + fb[768 + 64 + o];
      float gin = g2[nt + 8][reg]  + fb[768 + 128 + o];
      float ghr = acc[nt + 4][reg]  + fb[960 + o];
      float ghz = acc[nt + 8][reg]  + fb[960 + 64 + o];
      float ghn = acc[nt + 12][reg] + fb[960 + 128 + o];
      float rr = sigm(gir + ghr);
      float zg = sigm(giz + ghz);
      float nnv = tanhf(gin + rr * ghn);
      float hv = h[gidx];
      h[gidx] = (1.f - zg) * nnv + zg * hv;
    }
  }
}

// ---------------- fused Set2Set (6 steps) + memory LSTM, fp32 ----------------
__global__ __launch_bounds__(256) void s2s_kernel(
    const float* __restrict__ h,
    const float* __restrict__ wih, const float* __restrict__ whhp,
    const float* __restrict__ mwih, const float* __restrict__ fb,
    float* __restrict__ hx_f32, float* __restrict__ dout) {
  __shared__ float outL[64][65];
  __shared__ float qs[128];
  __shared__ float hsv[64], csv[64], sg[256], sa[64];
  __shared__ float spart[4][64];
  const int t = threadIdx.x;
  const int g = blockIdx.x;
  for (int idx = t; idx < 64 * 64; idx += 256) outL[idx >> 6][idx & 63] = h[g * 4096 + idx];
  if (t < 128) qs[t] = 0.f;
  if (t < 64) { hsv[t] = 0.f; csv[t] = 0.f; }
  __syncthreads();
  for (int step = 0; step < 6; step++) {
    float acc = fb[1152 + t] + fb[1408 + t];
    const float* wr = wih + t * 128;
#pragma unroll 8
    for (int j = 0; j < 128; j++) acc += qs[j] * wr[j];
    const float* wr2 = whhp + t * 64;
#pragma unroll 8
    for (int j = 0; j < 64; j++) acc += hsv[j] * wr2[j];
    sg[t] = acc;
    __syncthreads();
    if (t < 64) {
      float cn = sigm(sg[64 + t]) * csv[t] + sigm(sg[t]) * tanhf(sg[128 + t]);
      csv[t] = cn;
      hsv[t] = sigm(sg[192 + t]) * tanhf(cn);
    }
    __syncthreads();
    if (t < 64) {
      float e = 0.f;
      for (int d2 = 0; d2 < 64; d2++) e += outL[t][d2] * hsv[d2];
      float mx = e;
      for (int off = 32; off > 0; off >>= 1) mx = fmaxf(mx, __shfl_xor(mx, off));
      float a = __expf(e - mx);
      float s = a;
      for (int off = 32; off > 0; off >>= 1) s += __shfl_xor(s, off);
      sa[t] = a / s;
    }
    __syncthreads();
    {
      int o = t & 63, part = t >> 6;
      float r = 0.f;
      for (int n2 = part * 16; n2 < part * 16 + 16; n2++) r += sa[n2] * outL[n2][o];
      spart[part][o] = r;
    }
    __syncthreads();
    if (t < 64) {
      qs[t] = hsv[t];
      qs[64 + t] = spart[0][t] + spart[1][t] + spart[2][t] + spart[3][t];
    }
    __syncthreads();
  }
  float acc = fb[1664 + t] + fb[1920 + t];
  const float* wr = mwih + t * 128;
#pragma unroll 8
  for (int j = 0; j < 128; j++) acc += qs[j] * wr[j];
  sg[t] = acc;
  __syncthreads();
  if (t < 64) {
    float cn = sigm(sg[t]) * tanhf(sg[128 + t]);
    float hn = sigm(sg[192 + t]) * tanhf(cn);
    hx_f32[g * 64 + t] = hn;
    dout[TTOT * 6 + g * 64 + t] = hn;
    dout[TTOT * 6 + NG * 64 + g * 64 + t] = cn;
  }
}

// ---------------- head: faithful permute/reshape + lin1 + lin2, fp32 ----------------
__global__ __launch_bounds__(64) void head_kernel(
    const float* __restrict__ h, const float* __restrict__ hx_f32,
    const int* __restrict__ nonring, const int* __restrict__ nrbidx,
    const float* __restrict__ l1w, const float* __restrict__ l2w,
    const float* __restrict__ fb, float* __restrict__ dout) {
  __shared__ float feat[320];
  __shared__ float so1[64];
  const int r = blockIdx.x;
  const int lane = threadIdx.x;
  const int blk = r % 48, di = r / 48;
  const int tt = blk * 64 + lane;
  feat[lane * 5] = hx_f32[nrbidx[tt] * 64 + di];
#pragma unroll
  for (int s = 1; s <= 4; s++)
    feat[lane * 5 + s] = h[nonring[(s - 1) * TTOT + tt] * 64 + di];
  __syncthreads();
  float acc = fb[2176 + lane];
  const float* wr = l1w + lane * 320;
#pragma unroll 8
  for (int c = 0; c < 320; c++) acc += feat[c] * wr[c];
  so1[lane] = fmaxf(acc, 0.f);
  __syncthreads();
  if (lane < 6) {
    float a2 = fb[2240 + lane];
    for (int j = 0; j < 64; j++) a2 += so1[j] * l2w[lane * 64 + j];
    dout[r * 6 + lane] = a2;
  }
}

extern "C" void kernel_launch(void* const* d_in, const int* in_sizes, int n_in,
                              void* d_out, int out_size, void* d_ws, size_t ws_size,
                              hipStream_t stream) {
  (void)in_sizes; (void)n_in; (void)out_size;
  const float* x         = (const float*)d_in[0];
  const float* edge_attr = (const float*)d_in[1];
  const int* edge_index  = (const int*)d_in[2];
  const int* nonring     = (const int*)d_in[4];
  const int* nrbidx      = (const int*)d_in[5];
  float* out = (float*)d_out;

  char* ws = (char*)d_ws;
  float*  h      = (float*)(ws + WS_H);
  float*  agg    = (float*)(ws + WS_AGG);
  __bf16* w2hi   = (__bf16*)(ws + WS_W2HI);
  __bf16* w2lo   = (__bf16*)(ws + WS_W2LO);
  __bf16* rtHi   = (__bf16*)(ws + WS_RTHI);
  __bf16* rtLo   = (__bf16*)(ws + WS_RTLO);
  __bf16* whhHi  = (__bf16*)(ws + WS_WHHHI);
  __bf16* whhLo  = (__bf16*)(ws + WS_WHHLO);
  __bf16* wihHi  = (__bf16*)(ws + WS_WIHHI);
  __bf16* wihLo  = (__bf16*)(ws + WS_WIHLO);
  float*  swihF  = (float*)(ws + WS_SWIH);
  float*  swhhF  = (float*)(ws + WS_SWHH);
  float*  mwihF  = (float*)(ws + WS_MWIH);
  float*  l1wF   = (float*)(ws + WS_L1WF);
  float*  l2wF   = (float*)(ws + WS_L2WF);
  float*  fb     = (float*)(ws + WS_FB);
  float*  deg    = (float*)(ws + WS_DEG);
  float*  hx_f32 = (float*)(ws + WS_HX);
  if (ws_size < (size_t)WS_NEED) return;

  Srcs S;
  S.p[0] = d_in[8];   S.p[1] = d_in[9];   S.p[2] = d_in[10];  S.p[3] = d_in[11];
  S.p[4] = d_in[12];  S.p[5] = d_in[13];  S.p[6] = d_in[14];  S.p[7] = d_in[15];
  S.p[8] = d_in[16];  S.p[9] = d_in[17];  S.p[10] = d_in[18]; S.p[11] = d_in[19];
  S.p[12] = d_in[20]; S.p[13] = d_in[21]; S.p[14] = d_in[22]; S.p[15] = d_in[23];
  S.p[16] = d_in[24]; S.p[17] = d_in[26]; S.p[18] = d_in[27]; S.p[19] = d_in[28];
  S.p[20] = d_in[29]; S.p[21] = d_in[30]; S.p[22] = d_in[31];
  pack_kernel<<<(399942 + 255) / 256, 256, 0, stream>>>(S, ws);

  init_kernel<<<NNODE * D / 256, 256, 0, stream>>>(x, fb, h);
  hipMemsetAsync(deg, 0, NNODE * 4, stream);
  deg_kernel<<<NEDGE / 256, 256, 0, stream>>>(edge_index, deg);

  for (int it = 0; it < 6; it++) {
    hipMemsetAsync(agg, 0, NNODE * D * 4, stream);
    msg_kernel<<<NEDGE / 128, 512, 0, stream>>>(h, edge_attr, fb, w2hi, w2lo,
                                                edge_index, agg);
    update_kernel<<<NNODE / 64, 256, 0, stream>>>(h, agg, deg, rtHi, rtLo,
                                                  whhHi, whhLo, wihHi, wihLo, fb);
  }

  s2s_kernel<<<NG, 256, 0, stream>>>(h, swihF, swhhF, mwihF, fb, hx_f32, out);
  head_kernel<<<TTOT, 64, 0, stream>>>(h, hx_f32, nonring, nrbidx, l1wF, l2wF, fb, out);
}

// Round 6
// 716.237 us; speedup vs baseline: 1.1135x; 1.1135x over previous
//
#include <hip/hip_runtime.h>

#define NNODE 16384
#define NEDGE 32768
#define NG    256
#define TPGx  12
#define TTOT  (NG * TPGx)   // 3072
#define D     64
#define KTOT  4160          // 64*64 + 64 bias tail

typedef __bf16 b8 __attribute__((ext_vector_type(8)));
typedef float  f4 __attribute__((ext_vector_type(4)));

static __device__ __forceinline__ float sigm(float x) { return 1.f / (1.f + __expf(-x)); }

static __device__ __forceinline__ f4 mfma16(b8 a, b8 b, f4 c) {
  return __builtin_amdgcn_mfma_f32_16x16x32_bf16(a, b, c, 0, 0, 0);
}

// async global->LDS, 16B per lane; lds base must be wave-uniform (HW adds lane*16)
static __device__ __forceinline__ void gload_lds16(const __bf16* g, __bf16* l) {
  __builtin_amdgcn_global_load_lds(
      (const __attribute__((address_space(1))) unsigned int*)g,
      (__attribute__((address_space(3))) unsigned int*)l, 16, 0, 0);
}

// ---------------- workspace layout (byte offsets) ----------------
#define WS_H      0          // float [N*64]   4 MiB
#define WS_AGG    4194304    // float [N*64]   4 MiB
#define WS_W2     8388608    // bf16  [65 tiles * 8192]; tile i: [hi 4096][lo 4096], idx=(kc*64+o)*8+j
#define WS_RTHI   9453568    // bf16  [64*64]  rt[o][i]
#define WS_RTLO   9461760
#define WS_WHHHI  9469952    // bf16  [192*64] natural [oo][i]
#define WS_WHHLO  9494528
#define WS_WIHHI  9519104    // bf16  [192*64]
#define WS_WIHLO  9543680
#define WS_SWIH   9568256    // f32   [256*128]
#define WS_SWHH   9699328    // f32   [256*64]
#define WS_MWIH   9764864    // f32   [256*128]
#define WS_L1WF   9895936    // f32   [64*320]
#define WS_L2WF   9977856    // f32   [6*64]
#define WS_FB     9979392    // f32   [2246]
#define WS_DEG    9988608    // f32   [N]
#define WS_HX     10054144   // f32   [G*64]
#define WS_NEED   10119680
// fb sub-offsets (floats): lin0w 0, lin0b 192, e1w 256, e1b 640, convb 704,
// gbih 768, gbhh 960, s2sbih 1152, s2sbhh 1408, membih 1664, membhh 1920,
// l1b 2176, l2b 2240

// ---------------- pack fp32 params; split GEMM weights into bf16 hi+lo ----------------
struct Srcs { const void* p[23]; };

__device__ __constant__ const int kCum[24] = {
    0, 192, 256, 640, 704, 262848, 266944, 271040, 271104, 283392, 295680,
    295872, 296064, 328832, 345216, 345472, 345728, 378496, 378752, 379008,
    399488, 399552, 399936, 399942};

__global__ __launch_bounds__(256) void pack_kernel(Srcs S, char* __restrict__ ws) {
  int idx = blockIdx.x * 256 + threadIdx.x;
  if (idx >= 399942) return;
  int r = 0, base = 0;
#pragma unroll
  for (int k = 0; k < 23; k++)
    if (idx >= kCum[k]) { r = k; base = kCum[k]; }
  int li = idx - base;
  float v = ((const float*)S.p[r])[li];
  __bf16 hi = (__bf16)v;
  __bf16 lo = (__bf16)(v - (float)hi);

  float*  fb    = (float*)(ws + WS_FB);
  __bf16* w2    = (__bf16*)(ws + WS_W2);
  __bf16* rtHi  = (__bf16*)(ws + WS_RTHI);
  __bf16* rtLo  = (__bf16*)(ws + WS_RTLO);
  __bf16* whhHi = (__bf16*)(ws + WS_WHHHI);
  __bf16* whhLo = (__bf16*)(ws + WS_WHHLO);
  __bf16* wihHi = (__bf16*)(ws + WS_WIHHI);
  __bf16* wihLo = (__bf16*)(ws + WS_WIHLO);
  float*  swih  = (float*)(ws + WS_SWIH);
  float*  swhh  = (float*)(ws + WS_SWHH);
  float*  mwih  = (float*)(ws + WS_MWIH);
  float*  l1w   = (float*)(ws + WS_L1WF);
  float*  l2w   = (float*)(ws + WS_L2WF);

  switch (r) {
    case 0: fb[li] = v; break;          // lin0_w
    case 1: fb[192 + li] = v; break;    // lin0_b
    case 2: fb[256 + li] = v; break;    // e1_w
    case 3: fb[640 + li] = v; break;    // e1_b
    case 4: {                           // e2_w flat (i*64+o)*64+k -> tile i, idx=((k>>3)*64+o)*8+(k&7)
      int i = li >> 12, o = (li >> 6) & 63, k = li & 63;
      int e = i * 8192 + (((k >> 3) * 64 + o) << 3) + (k & 7);
      w2[e] = hi; w2[e + 4096] = lo;
    } break;
    case 5: {                           // e2_b flat k*64+o -> tile 64
      int k = li >> 6, o = li & 63;
      int e = 64 * 8192 + (((k >> 3) * 64 + o) << 3) + (k & 7);
      w2[e] = hi; w2[e + 4096] = lo;
    } break;
    case 6: {                           // root_w [i][o] -> rt[o*64+i]
      int i = li >> 6, o = li & 63;
      rtHi[o * 64 + i] = hi; rtLo[o * 64 + i] = lo;
    } break;
    case 7: fb[704 + li] = v; break;    // conv_b
    case 8: wihHi[li] = hi; wihLo[li] = lo; break;   // gru_wih [oo][i]
    case 9: whhHi[li] = hi; whhLo[li] = lo; break;   // gru_whh [oo][i]
    case 10: fb[768 + li] = v; break;   // gru_bih
    case 11: fb[960 + li] = v; break;   // gru_bhh
    case 12: swih[li] = v; break;
    case 13: swhh[li] = v; break;
    case 14: fb[1152 + li] = v; break;  // s2s_bih
    case 15: fb[1408 + li] = v; break;  // s2s_bhh
    case 16: mwih[li] = v; break;
    case 17: fb[1664 + li] = v; break;  // mem_bih
    case 18: fb[1920 + li] = v; break;  // mem_bhh
    case 19: l1w[li] = v; break;
    case 20: fb[2176 + li] = v; break;  // lin1_b
    case 21: l2w[li] = v; break;
    case 22: fb[2240 + li] = v; break;  // lin2_b
  }
}

// ---------------- node init: h = relu(x @ lin0_w.T + lin0_b), fp32 ----------------
__global__ __launch_bounds__(256) void init_kernel(
    const float* __restrict__ x, const float* __restrict__ fb,
    float* __restrict__ h) {
  int idx = blockIdx.x * 256 + threadIdx.x;  // n*64+o
  int n = idx >> 6, o = idx & 63;
  float acc = fb[192 + o];
#pragma unroll
  for (int j = 0; j < 3; j++) acc += x[n * 3 + j] * fb[o * 3 + j];
  h[idx] = fmaxf(acc, 0.f);
}

// ---------------- degree ----------------
__global__ __launch_bounds__(256) void deg_kernel(const int* __restrict__ edge_index,
                                                  float* __restrict__ deg) {
  int e = blockIdx.x * 256 + threadIdx.x;
  if (e < NEDGE) atomicAdd(&deg[edge_index[NEDGE + e]], 1.0f);
}

// ---------------- message GEMM, split-bf16, double-buffered async B staging ----------
// 256 threads = 4 waves; 64 edges/block; grid = 512.
__global__ __launch_bounds__(256) void msg_kernel(
    const float* __restrict__ h, const float* __restrict__ ea,
    const float* __restrict__ fb, const __bf16* __restrict__ w2,
    const int* __restrict__ edge_index, float* __restrict__ agg) {
  __shared__ float  sOut[64][68];
  __shared__ __bf16 sB[2][8192];
  const int tid = threadIdx.x;
  const int wave = tid >> 6, lane = tid & 63;
  const int m15 = lane & 15, quad = lane >> 4;
  const int eb = blockIdx.x * 64;
  {  // stage out[src] fp32 for 64 edges
    int r = tid >> 2, c0 = (tid & 3) * 16;
    int srcn = edge_index[eb + r];
#pragma unroll
    for (int c = c0; c < c0 + 16; c += 4)
      *(float4*)&sOut[r][c] = *(const float4*)&h[srcn * D + c];
  }
  const int erow = wave * 16 + m15;
  const int e = eb + erow;
  // recompute edge hidden in fp32 for this lane's k-slices
  float hid0[8], hid1[8];
  {
    float eav[6];
#pragma unroll
    for (int j = 0; j < 6; j++) eav[j] = ea[e * 6 + j];
#pragma unroll
    for (int j = 0; j < 8; j++) {
      int k0 = quad * 8 + j, k1 = 32 + quad * 8 + j;
      float a0 = fb[640 + k0], a1 = fb[640 + k1];
#pragma unroll
      for (int jj = 0; jj < 6; jj++) {
        a0 += eav[jj] * fb[256 + k0 * 6 + jj];
        a1 += eav[jj] * fb[256 + k1 * 6 + jj];
      }
      hid0[j] = fmaxf(a0, 0.f);
      hid1[j] = fmaxf(a1, 0.f);
    }
  }
  {  // prefetch tile 0 (4 chunks of 512 elems per wave)
#pragma unroll
    for (int j = 0; j < 4; j++) {
      int ch = wave * 4 + j;
      gload_lds16(w2 + ch * 512 + lane * 8, &sB[0][ch * 512]);
    }
  }
  __syncthreads();
  f4 zz = {0.f, 0.f, 0.f, 0.f};
  f4 acc0 = zz, acc1 = zz, acc2 = zz, acc3 = zz;
  for (int i = 0; i <= 64; i++) {
    const int cur = i & 1;
    if (i < 64) {  // async prefetch tile i+1 into the other buffer
#pragma unroll
      for (int j = 0; j < 4; j++) {
        int ch = wave * 4 + j;
        gload_lds16(w2 + (i + 1) * 8192 + ch * 512 + lane * 8, &sB[cur ^ 1][ch * 512]);
      }
    }
    // build fp32 z slices, split exactly via truncation (zh = top16, zl exact)
    float zs0[8], zs1[8];
    if (i < 64) {
      float os = sOut[erow][i];
#pragma unroll
      for (int j = 0; j < 8; j++) { zs0[j] = os * hid0[j]; zs1[j] = os * hid1[j]; }
    } else {  // bias tail: z = out_src
#pragma unroll
      for (int j = 0; j < 8; j++) {
        zs0[j] = sOut[erow][quad * 8 + j];
        zs1[j] = sOut[erow][32 + quad * 8 + j];
      }
    }
    union { b8 v; unsigned short s[8]; } a0h, a1h;
    b8 a0l, a1l;
#pragma unroll
    for (int j = 0; j < 8; j++) {
      unsigned u0 = __float_as_uint(zs0[j]);
      a0h.s[j] = (unsigned short)(u0 >> 16);
      a0l[j] = (__bf16)(zs0[j] - __uint_as_float(u0 & 0xffff0000u));
      unsigned u1 = __float_as_uint(zs1[j]);
      a1h.s[j] = (unsigned short)(u1 >> 16);
      a1l[j] = (__bf16)(zs1[j] - __uint_as_float(u1 & 0xffff0000u));
    }
    const __bf16* base = &sB[cur][0];
    const int q512 = quad * 512;
#pragma unroll
    for (int nt = 0; nt < 4; nt++) {
      int br8 = (nt * 16 + m15) * 8;
      b8 bh0 = *(const b8*)(base + q512 + br8);           // hi, half0 (kc=quad)
      b8 bh1 = *(const b8*)(base + 2048 + q512 + br8);    // hi, half1 (kc=4+quad)
      b8 bl0 = *(const b8*)(base + 4096 + q512 + br8);    // lo, half0
      b8 bl1 = *(const b8*)(base + 6144 + q512 + br8);    // lo, half1
      f4 a = (nt == 0) ? acc0 : (nt == 1) ? acc1 : (nt == 2) ? acc2 : acc3;
      a = mfma16(a0h.v, bh0, a);
      a = mfma16(a0l,   bh0, a);
      a = mfma16(a0h.v, bl0, a);
      a = mfma16(a1h.v, bh1, a);
      a = mfma16(a1l,   bh1, a);
      a = mfma16(a1h.v, bl1, a);
      if (nt == 0) acc0 = a; else if (nt == 1) acc1 = a; else if (nt == 2) acc2 = a; else acc3 = a;
    }
    __syncthreads();  // release cur for re-staging; ensures next buffer landed
  }
#pragma unroll
  for (int reg = 0; reg < 4; reg++) {
    int ee = eb + wave * 16 + quad * 4 + reg;
    int dn = edge_index[NEDGE + ee];
    float* ap = agg + dn * D;
    atomicAdd(ap + m15,      acc0[reg]);
    atomicAdd(ap + 16 + m15, acc1[reg]);
    atomicAdd(ap + 32 + m15, acc2[reg]);
    atomicAdd(ap + 48 + m15, acc3[reg]);
  }
}

// ---------------- node update, split-bf16 MFMA; zeroes agg for the next iteration ----
__global__ __launch_bounds__(256) void update_kernel(
    float* __restrict__ h, float* __restrict__ agg, const float* __restrict__ deg,
    const __bf16* __restrict__ rtHi, const __bf16* __restrict__ rtLo,
    const __bf16* __restrict__ whhHi, const __bf16* __restrict__ whhLo,
    const __bf16* __restrict__ wihHi, const __bf16* __restrict__ wihLo,
    const float* __restrict__ fb) {
  __shared__ float buf[64][68];  // sH, then (after barrier) sM
  const int tid = threadIdx.x;
  const int wave = tid >> 6, lane = tid & 63;
  const int m15 = lane & 15, quad = lane >> 4;
  const int nb = blockIdx.x * 64;
  {
    int r = tid >> 2, c0 = (tid & 3) * 16;
#pragma unroll
    for (int c = c0; c < c0 + 16; c += 4)
      *(float4*)&buf[r][c] = *(const float4*)&h[(nb + r) * D + c];
  }
  __syncthreads();
  const int mrow = wave * 16 + m15;
  b8 a0h, a0l, a1h, a1l;
#pragma unroll
  for (int j = 0; j < 8; j++) {
    float v0 = buf[mrow][quad * 8 + j];
    float v1 = buf[mrow][32 + quad * 8 + j];
    __bf16 h0 = (__bf16)v0; a0h[j] = h0; a0l[j] = (__bf16)(v0 - (float)h0);
    __bf16 h1 = (__bf16)v1; a1h[j] = h1; a1l[j] = (__bf16)(v1 - (float)h1);
  }
  f4 zz = {0.f, 0.f, 0.f, 0.f};
  f4 acc[16];
#pragma unroll
  for (int nt = 0; nt < 16; nt++) acc[nt] = zz;
#pragma unroll
  for (int nt = 0; nt < 16; nt++) {
    int nn = nt * 16 + m15;
    const __bf16* bh = (nt < 4) ? (rtHi + nn * D) : (whhHi + (nn - 64) * D);
    const __bf16* bl = (nt < 4) ? (rtLo + nn * D) : (whhLo + (nn - 64) * D);
    b8 bh0 = *(const b8*)(bh + quad * 8);
    b8 bl0 = *(const b8*)(bl + quad * 8);
    b8 bh1 = *(const b8*)(bh + 32 + quad * 8);
    b8 bl1 = *(const b8*)(bl + 32 + quad * 8);
    f4 a = acc[nt];
    a = mfma16(a0h, bh0, a);
    a = mfma16(a0l, bh0, a);
    a = mfma16(a0h, bl0, a);
    a = mfma16(a1h, bh1, a);
    a = mfma16(a1l, bh1, a);
    a = mfma16(a1h, bl1, a);
    acc[nt] = a;
  }
  __syncthreads();  // everyone done reading sH
  // m = relu(root + agg/deg + conv_b), fp32, into buf; zero agg behind us
#pragma unroll
  for (int nt = 0; nt < 4; nt++) {
#pragma unroll
    for (int reg = 0; reg < 4; reg++) {
      int nloc = wave * 16 + quad * 4 + reg;
      int o = nt * 16 + m15;
      float dg = fmaxf(deg[nb + nloc], 1.f);
      int aidx = (nb + nloc) * D + o;
      float v = acc[nt][reg] + agg[aidx] / dg + fb[704 + o];
      agg[aidx] = 0.f;
      buf[nloc][o] = fmaxf(v, 0.f);
    }
  }
  __syncthreads();
  b8 m0h, m0l, m1h, m1l;
#pragma unroll
  for (int j = 0; j < 8; j++) {
    float v0 = buf[mrow][quad * 8 + j];
    float v1 = buf[mrow][32 + quad * 8 + j];
    __bf16 h0 = (__bf16)v0; m0h[j] = h0; m0l[j] = (__bf16)(v0 - (float)h0);
    __bf16 h1 = (__bf16)v1; m1h[j] = h1; m1l[j] = (__bf16)(v1 - (float)h1);
  }
  f4 g2[12];
#pragma unroll
  for (int nt = 0; nt < 12; nt++) g2[nt] = zz;
#pragma unroll
  for (int nt = 0; nt < 12; nt++) {
    int nn = nt * 16 + m15;
    const __bf16* bh = wihHi + nn * D;
    const __bf16* bl = wihLo + nn * D;
    b8 bh0 = *(const b8*)(bh + quad * 8);
    b8 bl0 = *(const b8*)(bl + quad * 8);
    b8 bh1 = *(const b8*)(bh + 32 + quad * 8);
    b8 bl1 = *(const b8*)(bl + 32 + quad * 8);
    f4 a = g2[nt];
    a = mfma16(m0h, bh0, a);
    a = mfma16(m0l, bh0, a);
    a = mfma16(m0h, bl0, a);
    a = mfma16(m1h, bh1, a);
    a = mfma16(m1l, bh1, a);
    a = mfma16(m1h, bl1, a);
    g2[nt] = a;
  }
#pragma unroll
  for (int nt = 0; nt < 4; nt++) {
#pragma unroll
    for (int reg = 0; reg < 4; reg++) {
      int nloc = wave * 16 + quad * 4 + reg;
      int o = nt * 16 + m15;
      int gidx = (nb + nloc) * D + o;
      float gir = g2[nt][reg]      + fb[768 + o];
      float giz = g2[nt + 4][reg]  + fb[768 + 64 + o];
      float gin = g2[nt + 8][reg]  + fb[768 + 128 + o];
      float ghr = acc[nt + 4][reg]  + fb[960 + o];
      float ghz = acc[nt + 8][reg]  + fb[960 + 64 + o];
      float ghn = acc[nt + 12][reg] + fb[960 + 128 + o];
      float rr = sigm(gir + ghr);
      float zg = sigm(giz + ghz);
      float nnv = tanhf(gin + rr * ghn);
      float hv = h[gidx];
      h[gidx] = (1.f - zg) * nnv + zg * hv;
    }
  }
}

// ---------------- fused Set2Set (6 steps) + memory LSTM, fp32 ----------------
__global__ __launch_bounds__(256) void s2s_kernel(
    const float* __restrict__ h,
    const float* __restrict__ wih, const float* __restrict__ whhp,
    const float* __restrict__ mwih, const float* __restrict__ fb,
    float* __restrict__ hx_f32, float* __restrict__ dout) {
  __shared__ float outL[64][65];
  __shared__ float qs[128];
  __shared__ float hsv[64], csv[64], sg[256], sa[64];
  __shared__ float spart[4][64];
  const int t = threadIdx.x;
  const int g = blockIdx.x;
  for (int idx = t; idx < 64 * 64; idx += 256) outL[idx >> 6][idx & 63] = h[g * 4096 + idx];
  if (t < 128) qs[t] = 0.f;
  if (t < 64) { hsv[t] = 0.f; csv[t] = 0.f; }
  __syncthreads();
  for (int step = 0; step < 6; step++) {
    float acc = fb[1152 + t] + fb[1408 + t];
    const float* wr = wih + t * 128;
#pragma unroll 8
    for (int j = 0; j < 128; j++) acc += qs[j] * wr[j];
    const float* wr2 = whhp + t * 64;
#pragma unroll 8
    for (int j = 0; j < 64; j++) acc += hsv[j] * wr2[j];
    sg[t] = acc;
    __syncthreads();
    if (t < 64) {
      float cn = sigm(sg[64 + t]) * csv[t] + sigm(sg[t]) * tanhf(sg[128 + t]);
      csv[t] = cn;
      hsv[t] = sigm(sg[192 + t]) * tanhf(cn);
    }
    __syncthreads();
    if (t < 64) {
      float e = 0.f;
      for (int d2 = 0; d2 < 64; d2++) e += outL[t][d2] * hsv[d2];
      float mx = e;
      for (int off = 32; off > 0; off >>= 1) mx = fmaxf(mx, __shfl_xor(mx, off));
      float a = __expf(e - mx);
      float s = a;
      for (int off = 32; off > 0; off >>= 1) s += __shfl_xor(s, off);
      sa[t] = a / s;
    }
    __syncthreads();
    {
      int o = t & 63, part = t >> 6;
      float r = 0.f;
      for (int n2 = part * 16; n2 < part * 16 + 16; n2++) r += sa[n2] * outL[n2][o];
      spart[part][o] = r;
    }
    __syncthreads();
    if (t < 64) {
      qs[t] = hsv[t];
      qs[64 + t] = spart[0][t] + spart[1][t] + spart[2][t] + spart[3][t];
    }
    __syncthreads();
  }
  float acc = fb[1664 + t] + fb[1920 + t];
  const float* wr = mwih + t * 128;
#pragma unroll 8
  for (int j = 0; j < 128; j++) acc += qs[j] * wr[j];
  sg[t] = acc;
  __syncthreads();
  if (t < 64) {
    float cn = sigm(sg[t]) * tanhf(sg[128 + t]);
    float hn = sigm(sg[192 + t]) * tanhf(cn);
    hx_f32[g * 64 + t] = hn;
    dout[TTOT * 6 + g * 64 + t] = hn;
    dout[TTOT * 6 + NG * 64 + g * 64 + t] = cn;
  }
}

// ---------------- head: faithful permute/reshape + lin1 + lin2, fp32 ----------------
__global__ __launch_bounds__(64) void head_kernel(
    const float* __restrict__ h, const float* __restrict__ hx_f32,
    const int* __restrict__ nonring, const int* __restrict__ nrbidx,
    const float* __restrict__ l1w, const float* __restrict__ l2w,
    const float* __restrict__ fb, float* __restrict__ dout) {
  __shared__ float feat[320];
  __shared__ float so1[64];
  const int r = blockIdx.x;
  const int lane = threadIdx.x;
  const int blk = r % 48, di = r / 48;
  const int tt = blk * 64 + lane;
  feat[lane * 5] = hx_f32[nrbidx[tt] * 64 + di];
#pragma unroll
  for (int s = 1; s <= 4; s++)
    feat[lane * 5 + s] = h[nonring[(s - 1) * TTOT + tt] * 64 + di];
  __syncthreads();
  float acc = fb[2176 + lane];
  const float* wr = l1w + lane * 320;
#pragma unroll 8
  for (int c = 0; c < 320; c++) acc += feat[c] * wr[c];
  so1[lane] = fmaxf(acc, 0.f);
  __syncthreads();
  if (lane < 6) {
    float a2 = fb[2240 + lane];
    for (int j = 0; j < 64; j++) a2 += so1[j] * l2w[lane * 64 + j];
    dout[r * 6 + lane] = a2;
  }
}

extern "C" void kernel_launch(void* const* d_in, const int* in_sizes, int n_in,
                              void* d_out, int out_size, void* d_ws, size_t ws_size,
                              hipStream_t stream) {
  (void)in_sizes; (void)n_in; (void)out_size;
  const float* x         = (const float*)d_in[0];
  const float* edge_attr = (const float*)d_in[1];
  const int* edge_index  = (const int*)d_in[2];
  const int* nonring     = (const int*)d_in[4];
  const int* nrbidx      = (const int*)d_in[5];
  float* out = (float*)d_out;

  char* ws = (char*)d_ws;
  float*  h      = (float*)(ws + WS_H);
  float*  agg    = (float*)(ws + WS_AGG);
  __bf16* w2     = (__bf16*)(ws + WS_W2);
  __bf16* rtHi   = (__bf16*)(ws + WS_RTHI);
  __bf16* rtLo   = (__bf16*)(ws + WS_RTLO);
  __bf16* whhHi  = (__bf16*)(ws + WS_WHHHI);
  __bf16* whhLo  = (__bf16*)(ws + WS_WHHLO);
  __bf16* wihHi  = (__bf16*)(ws + WS_WIHHI);
  __bf16* wihLo  = (__bf16*)(ws + WS_WIHLO);
  float*  swihF  = (float*)(ws + WS_SWIH);
  float*  swhhF  = (float*)(ws + WS_SWHH);
  float*  mwihF  = (float*)(ws + WS_MWIH);
  float*  l1wF   = (float*)(ws + WS_L1WF);
  float*  l2wF   = (float*)(ws + WS_L2WF);
  float*  fb     = (float*)(ws + WS_FB);
  float*  deg    = (float*)(ws + WS_DEG);
  float*  hx_f32 = (float*)(ws + WS_HX);
  if (ws_size < (size_t)WS_NEED) return;

  Srcs S;
  S.p[0] = d_in[8];   S.p[1] = d_in[9];   S.p[2] = d_in[10];  S.p[3] = d_in[11];
  S.p[4] = d_in[12];  S.p[5] = d_in[13];  S.p[6] = d_in[14];  S.p[7] = d_in[15];
  S.p[8] = d_in[16];  S.p[9] = d_in[17];  S.p[10] = d_in[18]; S.p[11] = d_in[19];
  S.p[12] = d_in[20]; S.p[13] = d_in[21]; S.p[14] = d_in[22]; S.p[15] = d_in[23];
  S.p[16] = d_in[24]; S.p[17] = d_in[26]; S.p[18] = d_in[27]; S.p[19] = d_in[28];
  S.p[20] = d_in[29]; S.p[21] = d_in[30]; S.p[22] = d_in[31];
  pack_kernel<<<(399942 + 255) / 256, 256, 0, stream>>>(S, ws);

  init_kernel<<<NNODE * D / 256, 256, 0, stream>>>(x, fb, h);
  hipMemsetAsync(deg, 0, NNODE * 4, stream);
  hipMemsetAsync(agg, 0, NNODE * D * 4, stream);
  deg_kernel<<<NEDGE / 256, 256, 0, stream>>>(edge_index, deg);

  for (int it = 0; it < 6; it++) {
    msg_kernel<<<NEDGE / 64, 256, 0, stream>>>(h, edge_attr, fb, w2, edge_index, agg);
    update_kernel<<<NNODE / 64, 256, 0, stream>>>(h, agg, deg, rtHi, rtLo,
                                                  whhHi, whhLo, wihHi, wihLo, fb);
  }

  s2s_kernel<<<NG, 256, 0, stream>>>(h, swihF, swhhF, mwihF, fb, hx_f32, out);
  head_kernel<<<TTOT, 64, 0, stream>>>(h, hx_f32, nonring, nrbidx, l1wF, l2wF, fb, out);
}

// Round 7
// 539.960 us; speedup vs baseline: 1.4770x; 1.3265x over previous
//
#include <hip/hip_runtime.h>

#define NNODE 16384
#define NEDGE 32768
#define NG    256
#define TPGx  12
#define TTOT  (NG * TPGx)   // 3072
#define D     64

typedef _Float16 h8 __attribute__((ext_vector_type(8)));
typedef float    f4 __attribute__((ext_vector_type(4)));

static __device__ __forceinline__ float sigm(float x) { return 1.f / (1.f + __expf(-x)); }

static __device__ __forceinline__ f4 mfma16h(h8 a, h8 b, f4 c) {
  return __builtin_amdgcn_mfma_f32_16x16x32_f16(a, b, c, 0, 0, 0);
}

// async global->LDS, 16B per lane; lds base wave-uniform (HW adds lane*16)
static __device__ __forceinline__ void gload_lds16(const void* g, void* l) {
  __builtin_amdgcn_global_load_lds(
      (const __attribute__((address_space(1))) unsigned int*)g,
      (__attribute__((address_space(3))) unsigned int*)l, 16, 0, 0);
}

// ---------------- workspace layout (byte offsets) ----------------
#define WS_H      0          // float [N*64]   4 MiB
#define WS_AGG    4194304    // float [N*64]   4 MiB
#define WS_W2     8388608    // fp16 [65 tiles * 4096]; tile i idx=((k>>3)*64+o)*8+(k&7)
#define WS_RT     8921088    // fp16 [64*64]  rt[o][i]
#define WS_WHH    8929280    // fp16 [192*64] natural [oo][i]
#define WS_WIH    8953856    // fp16 [192*64]
#define WS_SWIH   8978432    // f32 [256*128]
#define WS_SWHH   9109504    // f32 [256*64]
#define WS_MWIH   9175040    // f32 [256*128]
#define WS_L1WF   9306112    // f32 [64*320]
#define WS_L2WF   9388032    // f32 [6*64]
#define WS_FB     9389568    // f32 [2246]
#define WS_DEG    9398784    // f32 [N]
#define WS_HX     9464320    // f32 [G*64]
#define WS_NEED   9529856
// fb sub-offsets (floats): lin0w 0, lin0b 192, e1w 256, e1b 640, convb 704,
// gbih 768, gbhh 960, s2sbih 1152, s2sbhh 1408, membih 1664, membhh 1920,
// l1b 2176, l2b 2240

// ---------------- pack fp32 params; GEMM weights -> fp16 ----------------
struct Srcs { const void* p[23]; };

__device__ __constant__ const int kCum[24] = {
    0, 192, 256, 640, 704, 262848, 266944, 271040, 271104, 283392, 295680,
    295872, 296064, 328832, 345216, 345472, 345728, 378496, 378752, 379008,
    399488, 399552, 399936, 399942};

__global__ __launch_bounds__(256) void pack_kernel(Srcs S, char* __restrict__ ws) {
  int idx = blockIdx.x * 256 + threadIdx.x;
  if (idx >= 399942) return;
  int r = 0, base = 0;
#pragma unroll
  for (int k = 0; k < 23; k++)
    if (idx >= kCum[k]) { r = k; base = kCum[k]; }
  int li = idx - base;
  float v = ((const float*)S.p[r])[li];

  float*    fb   = (float*)(ws + WS_FB);
  _Float16* w2   = (_Float16*)(ws + WS_W2);
  _Float16* rtH  = (_Float16*)(ws + WS_RT);
  _Float16* whhH = (_Float16*)(ws + WS_WHH);
  _Float16* wihH = (_Float16*)(ws + WS_WIH);
  float*    swih = (float*)(ws + WS_SWIH);
  float*    swhh = (float*)(ws + WS_SWHH);
  float*    mwih = (float*)(ws + WS_MWIH);
  float*    l1w  = (float*)(ws + WS_L1WF);
  float*    l2w  = (float*)(ws + WS_L2WF);

  switch (r) {
    case 0: fb[li] = v; break;          // lin0_w
    case 1: fb[192 + li] = v; break;    // lin0_b
    case 2: fb[256 + li] = v; break;    // e1_w
    case 3: fb[640 + li] = v; break;    // e1_b
    case 4: {                           // e2_w flat (i*64+o)*64+k -> tile i
      int i = li >> 12, o = (li >> 6) & 63, k = li & 63;
      w2[i * 4096 + (((k >> 3) * 64 + o) << 3) + (k & 7)] = (_Float16)v;
    } break;
    case 5: {                           // e2_b flat k*64+o -> tile 64
      int k = li >> 6, o = li & 63;
      w2[64 * 4096 + (((k >> 3) * 64 + o) << 3) + (k & 7)] = (_Float16)v;
    } break;
    case 6: {                           // root_w [i][o] -> rt[o*64+i]
      int i = li >> 6, o = li & 63;
      rtH[o * 64 + i] = (_Float16)v;
    } break;
    case 7: fb[704 + li] = v; break;    // conv_b
    case 8: wihH[li] = (_Float16)v; break;   // gru_wih [oo][i]
    case 9: whhH[li] = (_Float16)v; break;   // gru_whh [oo][i]
    case 10: fb[768 + li] = v; break;   // gru_bih
    case 11: fb[960 + li] = v; break;   // gru_bhh
    case 12: swih[li] = v; break;
    case 13: swhh[li] = v; break;
    case 14: fb[1152 + li] = v; break;  // s2s_bih
    case 15: fb[1408 + li] = v; break;  // s2s_bhh
    case 16: mwih[li] = v; break;
    case 17: fb[1664 + li] = v; break;  // mem_bih
    case 18: fb[1920 + li] = v; break;  // mem_bhh
    case 19: l1w[li] = v; break;
    case 20: fb[2176 + li] = v; break;  // lin1_b
    case 21: l2w[li] = v; break;
    case 22: fb[2240 + li] = v; break;  // lin2_b
  }
}

// ---------------- node init: h = relu(x @ lin0_w.T + lin0_b), fp32 ----------------
__global__ __launch_bounds__(256) void init_kernel(
    const float* __restrict__ x, const float* __restrict__ fb,
    float* __restrict__ h) {
  int idx = blockIdx.x * 256 + threadIdx.x;  // n*64+o
  int n = idx >> 6, o = idx & 63;
  float acc = fb[192 + o];
#pragma unroll
  for (int j = 0; j < 3; j++) acc += x[n * 3 + j] * fb[o * 3 + j];
  h[idx] = fmaxf(acc, 0.f);
}

// ---------------- degree ----------------
__global__ __launch_bounds__(256) void deg_kernel(const int* __restrict__ edge_index,
                                                  float* __restrict__ deg) {
  int e = blockIdx.x * 256 + threadIdx.x;
  if (e < NEDGE) atomicAdd(&deg[edge_index[NEDGE + e]], 1.0f);
}

// ---------------- message GEMM, fp16, 4-tile phases, async dbuf staging ----------
// 256 threads = 4 waves; 64 edges/block; grid = 512.
__global__ __launch_bounds__(256) void msg_kernel(
    const float* __restrict__ h, const float* __restrict__ ea,
    const float* __restrict__ fb, const _Float16* __restrict__ w2,
    const int* __restrict__ edge_index, float* __restrict__ agg) {
  __shared__ _Float16 sOut[64][72];
  __shared__ _Float16 sB[2][16384];   // 2 phase-buffers x 4 tiles x 4096
  const int tid = threadIdx.x;
  const int wave = tid >> 6, lane = tid & 63;
  const int m15 = lane & 15, quad = lane >> 4;
  const int eb = blockIdx.x * 64;
  {  // stage out[src] as fp16 for 64 edges
    int r = tid >> 2, c0 = (tid & 3) * 16;
    int srcn = edge_index[eb + r];
#pragma unroll
    for (int c = c0; c < c0 + 16; c += 4) {
      float4 v = *(const float4*)&h[srcn * D + c];
      sOut[r][c]     = (_Float16)v.x;
      sOut[r][c + 1] = (_Float16)v.y;
      sOut[r][c + 2] = (_Float16)v.z;
      sOut[r][c + 3] = (_Float16)v.w;
    }
  }
  const int erow = wave * 16 + m15;
  const int e = eb + erow;
  // recompute edge hidden in fp32 for this lane's k-slices
  float hid0[8], hid1[8];
  {
    float eav[6];
#pragma unroll
    for (int j = 0; j < 6; j++) eav[j] = ea[e * 6 + j];
#pragma unroll
    for (int j = 0; j < 8; j++) {
      int k0 = quad * 8 + j, k1 = 32 + quad * 8 + j;
      float a0 = fb[640 + k0], a1 = fb[640 + k1];
#pragma unroll
      for (int jj = 0; jj < 6; jj++) {
        a0 += eav[jj] * fb[256 + k0 * 6 + jj];
        a1 += eav[jj] * fb[256 + k1 * 6 + jj];
      }
      hid0[j] = fmaxf(a0, 0.f);
      hid1[j] = fmaxf(a1, 0.f);
    }
  }
  // prefetch phase 0 (tiles 0..3): 32 chunks of 512 fp16
  for (int c = wave; c < 32; c += 4)
    gload_lds16(w2 + c * 512 + lane * 8, &sB[0][c * 512]);
  __syncthreads();
  f4 zz = {0.f, 0.f, 0.f, 0.f};
  f4 acc0 = zz, acc1 = zz, acc2 = zz, acc3 = zz;
  for (int p = 0; p < 17; p++) {
    const int cur = p & 1;
    if (p < 16) {  // async prefetch next phase
      int nch = (p == 15) ? 8 : 32;  // phase 16 has 1 tile
      const _Float16* src = w2 + (p + 1) * 4 * 4096;
      for (int c = wave; c < nch; c += 4)
        gload_lds16(src + c * 512 + lane * 8, &sB[cur ^ 1][c * 512]);
    }
    const int cnt = (p == 16) ? 1 : 4;
    for (int t = 0; t < cnt; t++) {
      const int i = p * 4 + t;
      h8 a0, a1;
      if (i < 64) {
        float os = (float)sOut[erow][i];
#pragma unroll
        for (int j = 0; j < 8; j++) {
          a0[j] = (_Float16)(os * hid0[j]);
          a1[j] = (_Float16)(os * hid1[j]);
        }
      } else {  // bias tail: z = out_src
#pragma unroll
        for (int j = 0; j < 8; j++) {
          a0[j] = sOut[erow][quad * 8 + j];
          a1[j] = sOut[erow][32 + quad * 8 + j];
        }
      }
      const _Float16* base = &sB[cur][t * 4096];
      const int q512 = quad * 512;
#pragma unroll
      for (int nt = 0; nt < 4; nt++) {
        int br8 = (nt * 16 + m15) * 8;
        h8 bh0 = *(const h8*)(base + q512 + br8);          // kc = quad
        h8 bh1 = *(const h8*)(base + 2048 + q512 + br8);   // kc = 4+quad
        f4 a = (nt == 0) ? acc0 : (nt == 1) ? acc1 : (nt == 2) ? acc2 : acc3;
        a = mfma16h(a0, bh0, a);
        a = mfma16h(a1, bh1, a);
        if (nt == 0) acc0 = a; else if (nt == 1) acc1 = a; else if (nt == 2) acc2 = a; else acc3 = a;
      }
    }
    __syncthreads();  // phase boundary: buffer reuse + prefetch completion
  }
#pragma unroll
  for (int reg = 0; reg < 4; reg++) {
    int ee = eb + wave * 16 + quad * 4 + reg;
    int dn = edge_index[NEDGE + ee];
    float* ap = agg + dn * D;
    atomicAdd(ap + m15,      acc0[reg]);
    atomicAdd(ap + 16 + m15, acc1[reg]);
    atomicAdd(ap + 32 + m15, acc2[reg]);
    atomicAdd(ap + 48 + m15, acc3[reg]);
  }
}

// ---------------- node update, fp16 MFMA; zeroes agg for the next iteration ----
__global__ __launch_bounds__(256) void update_kernel(
    float* __restrict__ h, float* __restrict__ agg, const float* __restrict__ deg,
    const _Float16* __restrict__ rtH, const _Float16* __restrict__ whhH,
    const _Float16* __restrict__ wihH, const float* __restrict__ fb) {
  __shared__ float buf[64][68];  // sH, then (after barrier) sM
  const int tid = threadIdx.x;
  const int wave = tid >> 6, lane = tid & 63;
  const int m15 = lane & 15, quad = lane >> 4;
  const int nb = blockIdx.x * 64;
  {
    int r = tid >> 2, c0 = (tid & 3) * 16;
#pragma unroll
    for (int c = c0; c < c0 + 16; c += 4)
      *(float4*)&buf[r][c] = *(const float4*)&h[(nb + r) * D + c];
  }
  __syncthreads();
  const int mrow = wave * 16 + m15;
  h8 a0, a1;
#pragma unroll
  for (int j = 0; j < 8; j++) {
    a0[j] = (_Float16)buf[mrow][quad * 8 + j];
    a1[j] = (_Float16)buf[mrow][32 + quad * 8 + j];
  }
  f4 zz = {0.f, 0.f, 0.f, 0.f};
  f4 acc[16];
#pragma unroll
  for (int nt = 0; nt < 16; nt++) acc[nt] = zz;
#pragma unroll
  for (int nt = 0; nt < 16; nt++) {
    int nn = nt * 16 + m15;
    const _Float16* bp = (nt < 4) ? (rtH + nn * D) : (whhH + (nn - 64) * D);
    h8 bh0 = *(const h8*)(bp + quad * 8);
    h8 bh1 = *(const h8*)(bp + 32 + quad * 8);
    f4 a = acc[nt];
    a = mfma16h(a0, bh0, a);
    a = mfma16h(a1, bh1, a);
    acc[nt] = a;
  }
  __syncthreads();  // everyone done reading sH
  // m = relu(root + agg/deg + conv_b), fp32, into buf; zero agg behind us
#pragma unroll
  for (int nt = 0; nt < 4; nt++) {
#pragma unroll
    for (int reg = 0; reg < 4; reg++) {
      int nloc = wave * 16 + quad * 4 + reg;
      int o = nt * 16 + m15;
      float dg = fmaxf(deg[nb + nloc], 1.f);
      int aidx = (nb + nloc) * D + o;
      float v = acc[nt][reg] + agg[aidx] / dg + fb[704 + o];
      agg[aidx] = 0.f;
      buf[nloc][o] = fmaxf(v, 0.f);
    }
  }
  __syncthreads();
  h8 m0, m1;
#pragma unroll
  for (int j = 0; j < 8; j++) {
    m0[j] = (_Float16)buf[mrow][quad * 8 + j];
    m1[j] = (_Float16)buf[mrow][32 + quad * 8 + j];
  }
  f4 g2[12];
#pragma unroll
  for (int nt = 0; nt < 12; nt++) g2[nt] = zz;
#pragma unroll
  for (int nt = 0; nt < 12; nt++) {
    int nn = nt * 16 + m15;
    const _Float16* bp = wihH + nn * D;
    h8 bh0 = *(const h8*)(bp + quad * 8);
    h8 bh1 = *(const h8*)(bp + 32 + quad * 8);
    f4 a = g2[nt];
    a = mfma16h(m0, bh0, a);
    a = mfma16h(m1, bh1, a);
    g2[nt] = a;
  }
#pragma unroll
  for (int nt = 0; nt < 4; nt++) {
#pragma unroll
    for (int reg = 0; reg < 4; reg++) {
      int nloc = wave * 16 + quad * 4 + reg;
      int o = nt * 16 + m15;
      int gidx = (nb + nloc) * D + o;
      float gir = g2[nt][reg]      + fb[768 + o];
      float giz = g2[nt + 4][reg]  + fb[768 + 64 + o];
      float gin = g2[nt + 8][reg]  + fb[768 + 128 + o];
      float ghr = acc[nt + 4][reg]  + fb[960 + o];
      float ghz = acc[nt + 8][reg]  + fb[960 + 64 + o];
      float ghn = acc[nt + 12][reg] + fb[960 + 128 + o];
      float rr = sigm(gir + ghr);
      float zg = sigm(giz + ghz);
      float nnv = tanhf(gin + rr * ghn);
      float hv = h[gidx];
      h[gidx] = (1.f - zg) * nnv + zg * hv;
    }
  }
}

// ---------------- fused Set2Set (6 steps) + memory LSTM, fp32 ----------------
__global__ __launch_bounds__(256) void s2s_kernel(
    const float* __restrict__ h,
    const float* __restrict__ wih, const float* __restrict__ whhp,
    const float* __restrict__ mwih, const float* __restrict__ fb,
    float* __restrict__ hx_f32, float* __restrict__ dout) {
  __shared__ float outL[64][65];
  __shared__ float qs[128];
  __shared__ float hsv[64], csv[64], sg[256], sa[64];
  __shared__ float spart[4][64];
  const int t = threadIdx.x;
  const int g = blockIdx.x;
  for (int idx = t; idx < 64 * 64; idx += 256) outL[idx >> 6][idx & 63] = h[g * 4096 + idx];
  if (t < 128) qs[t] = 0.f;
  if (t < 64) { hsv[t] = 0.f; csv[t] = 0.f; }
  __syncthreads();
  for (int step = 0; step < 6; step++) {
    float acc = fb[1152 + t] + fb[1408 + t];
    const float* wr = wih + t * 128;
#pragma unroll 8
    for (int j = 0; j < 128; j++) acc += qs[j] * wr[j];
    const float* wr2 = whhp + t * 64;
#pragma unroll 8
    for (int j = 0; j < 64; j++) acc += hsv[j] * wr2[j];
    sg[t] = acc;
    __syncthreads();
    if (t < 64) {
      float cn = sigm(sg[64 + t]) * csv[t] + sigm(sg[t]) * tanhf(sg[128 + t]);
      csv[t] = cn;
      hsv[t] = sigm(sg[192 + t]) * tanhf(cn);
    }
    __syncthreads();
    if (t < 64) {
      float e = 0.f;
      for (int d2 = 0; d2 < 64; d2++) e += outL[t][d2] * hsv[d2];
      float mx = e;
      for (int off = 32; off > 0; off >>= 1) mx = fmaxf(mx, __shfl_xor(mx, off));
      float a = __expf(e - mx);
      float s = a;
      for (int off = 32; off > 0; off >>= 1) s += __shfl_xor(s, off);
      sa[t] = a / s;
    }
    __syncthreads();
    {
      int o = t & 63, part = t >> 6;
      float r = 0.f;
      for (int n2 = part * 16; n2 < part * 16 + 16; n2++) r += sa[n2] * outL[n2][o];
      spart[part][o] = r;
    }
    __syncthreads();
    if (t < 64) {
      qs[t] = hsv[t];
      qs[64 + t] = spart[0][t] + spart[1][t] + spart[2][t] + spart[3][t];
    }
    __syncthreads();
  }
  float acc = fb[1664 + t] + fb[1920 + t];
  const float* wr = mwih + t * 128;
#pragma unroll 8
  for (int j = 0; j < 128; j++) acc += qs[j] * wr[j];
  sg[t] = acc;
  __syncthreads();
  if (t < 64) {
    float cn = sigm(sg[t]) * tanhf(sg[128 + t]);
    float hn = sigm(sg[192 + t]) * tanhf(cn);
    hx_f32[g * 64 + t] = hn;
    dout[TTOT * 6 + g * 64 + t] = hn;
    dout[TTOT * 6 + NG * 64 + g * 64 + t] = cn;
  }
}

// ---------------- head: faithful permute/reshape + lin1 + lin2, fp32 ----------------
__global__ __launch_bounds__(64) void head_kernel(
    const float* __restrict__ h, const float* __restrict__ hx_f32,
    const int* __restrict__ nonring, const int* __restrict__ nrbidx,
    const float* __restrict__ l1w, const float* __restrict__ l2w,
    const float* __restrict__ fb, float* __restrict__ dout) {
  __shared__ float feat[320];
  __shared__ float so1[64];
  const int r = blockIdx.x;
  const int lane = threadIdx.x;
  const int blk = r % 48, di = r / 48;
  const int tt = blk * 64 + lane;
  feat[lane * 5] = hx_f32[nrbidx[tt] * 64 + di];
#pragma unroll
  for (int s = 1; s <= 4; s++)
    feat[lane * 5 + s] = h[nonring[(s - 1) * TTOT + tt] * 64 + di];
  __syncthreads();
  float acc = fb[2176 + lane];
  const float* wr = l1w + lane * 320;
#pragma unroll 8
  for (int c = 0; c < 320; c++) acc += feat[c] * wr[c];
  so1[lane] = fmaxf(acc, 0.f);
  __syncthreads();
  if (lane < 6) {
    float a2 = fb[2240 + lane];
    for (int j = 0; j < 64; j++) a2 += so1[j] * l2w[lane * 64 + j];
    dout[r * 6 + lane] = a2;
  }
}

extern "C" void kernel_launch(void* const* d_in, const int* in_sizes, int n_in,
                              void* d_out, int out_size, void* d_ws, size_t ws_size,
                              hipStream_t stream) {
  (void)in_sizes; (void)n_in; (void)out_size;
  const float* x         = (const float*)d_in[0];
  const float* edge_attr = (const float*)d_in[1];
  const int* edge_index  = (const int*)d_in[2];
  const int* nonring     = (const int*)d_in[4];
  const int* nrbidx      = (const int*)d_in[5];
  float* out = (float*)d_out;

  char* ws = (char*)d_ws;
  float*    h      = (float*)(ws + WS_H);
  float*    agg    = (float*)(ws + WS_AGG);
  _Float16* w2     = (_Float16*)(ws + WS_W2);
  _Float16* rtH    = (_Float16*)(ws + WS_RT);
  _Float16* whhH   = (_Float16*)(ws + WS_WHH);
  _Float16* wihH   = (_Float16*)(ws + WS_WIH);
  float*    swihF  = (float*)(ws + WS_SWIH);
  float*    swhhF  = (float*)(ws + WS_SWHH);
  float*    mwihF  = (float*)(ws + WS_MWIH);
  float*    l1wF   = (float*)(ws + WS_L1WF);
  float*    l2wF   = (float*)(ws + WS_L2WF);
  float*    fb     = (float*)(ws + WS_FB);
  float*    deg    = (float*)(ws + WS_DEG);
  float*    hx_f32 = (float*)(ws + WS_HX);
  if (ws_size < (size_t)WS_NEED) return;

  Srcs S;
  S.p[0] = d_in[8];   S.p[1] = d_in[9];   S.p[2] = d_in[10];  S.p[3] = d_in[11];
  S.p[4] = d_in[12];  S.p[5] = d_in[13];  S.p[6] = d_in[14];  S.p[7] = d_in[15];
  S.p[8] = d_in[16];  S.p[9] = d_in[17];  S.p[10] = d_in[18]; S.p[11] = d_in[19];
  S.p[12] = d_in[20]; S.p[13] = d_in[21]; S.p[14] = d_in[22]; S.p[15] = d_in[23];
  S.p[16] = d_in[24]; S.p[17] = d_in[26]; S.p[18] = d_in[27]; S.p[19] = d_in[28];
  S.p[20] = d_in[29]; S.p[21] = d_in[30]; S.p[22] = d_in[31];
  pack_kernel<<<(399942 + 255) / 256, 256, 0, stream>>>(S, ws);

  init_kernel<<<NNODE * D / 256, 256, 0, stream>>>(x, fb, h);
  hipMemsetAsync(deg, 0, NNODE * 4, stream);
  hipMemsetAsync(agg, 0, NNODE * D * 4, stream);
  deg_kernel<<<NEDGE / 256, 256, 0, stream>>>(edge_index, deg);

  for (int it = 0; it < 6; it++) {
    msg_kernel<<<NEDGE / 64, 256, 0, stream>>>(h, edge_attr, fb, w2, edge_index, agg);
    update_kernel<<<NNODE / 64, 256, 0, stream>>>(h, agg, deg, rtH, whhH, wihH, fb);
  }

  s2s_kernel<<<NG, 256, 0, stream>>>(h, swihF, swhhF, mwihF, fb, hx_f32, out);
  head_kernel<<<TTOT, 64, 0, stream>>>(h, hx_f32, nonring, nrbidx, l1wF, l2wF, fb, out);
}

// Round 8
// 530.266 us; speedup vs baseline: 1.5041x; 1.0183x over previous
//
#include <hip/hip_runtime.h>

#define NNODE 16384
#define NEDGE 32768
#define NG    256
#define TPGx  12
#define TTOT  (NG * TPGx)   // 3072
#define D     64

typedef _Float16 h8 __attribute__((ext_vector_type(8)));
typedef float    f4 __attribute__((ext_vector_type(4)));

static __device__ __forceinline__ float sigm(float x) { return 1.f / (1.f + __expf(-x)); }

static __device__ __forceinline__ f4 mfma16h(h8 a, h8 b, f4 c) {
  return __builtin_amdgcn_mfma_f32_16x16x32_f16(a, b, c, 0, 0, 0);
}

static __device__ __forceinline__ h8 splat16(_Float16 x) {
  h8 v = {x, x, x, x, x, x, x, x};
  return v;
}

// async global->LDS, 16B per lane; lds base wave-uniform (HW adds lane*16)
static __device__ __forceinline__ void gload_lds16(const void* g, void* l) {
  __builtin_amdgcn_global_load_lds(
      (const __attribute__((address_space(1))) unsigned int*)g,
      (__attribute__((address_space(3))) unsigned int*)l, 16, 0, 0);
}

// ---------------- workspace layout (byte offsets) ----------------
#define WS_H      0          // float [N*64]   4 MiB
#define WS_AGG    4194304    // float [N*64]   4 MiB
#define WS_W2     8388608    // fp16 [65 tiles * 4096]; tile i idx=((k>>3)*64+o)*8+(k&7)
#define WS_RT     8921088    // fp16 [64*64]  rt[o][i]
#define WS_WHH    8929280    // fp16 [192*64] natural [oo][i]
#define WS_WIH    8953856    // fp16 [192*64]
#define WS_SWIHT  8978432    // f32 [128][256] transposed
#define WS_SWHHT  9109504    // f32 [64][256]  transposed
#define WS_MWIHT  9175040    // f32 [128][256] transposed
#define WS_L1WT   9306112    // f32 [320][64]  transposed
#define WS_L2WF   9388032    // f32 [6*64]
#define WS_FB     9389568    // f32 [2246]
#define WS_DEG    9398784    // f32 [N]
#define WS_HX     9464320    // f32 [G*64]
#define WS_NEED   9529856
// fb sub-offsets (floats): lin0w 0, lin0b 192, e1w 256, e1b 640, convb 704,
// gbih 768, gbhh 960, s2sbih 1152, s2sbhh 1408, membih 1664, membhh 1920,
// l1b 2176, l2b 2240

// ---------------- pack fp32 params; GEMM weights -> fp16; s2s/head transposed ------
struct Srcs { const void* p[23]; };

__device__ __constant__ const int kCum[24] = {
    0, 192, 256, 640, 704, 262848, 266944, 271040, 271104, 283392, 295680,
    295872, 296064, 328832, 345216, 345472, 345728, 378496, 378752, 379008,
    399488, 399552, 399936, 399942};

__global__ __launch_bounds__(256) void pack_kernel(Srcs S, char* __restrict__ ws) {
  int idx = blockIdx.x * 256 + threadIdx.x;
  if (idx >= 399942) return;
  int r = 0, base = 0;
#pragma unroll
  for (int k = 0; k < 23; k++)
    if (idx >= kCum[k]) { r = k; base = kCum[k]; }
  int li = idx - base;
  float v = ((const float*)S.p[r])[li];

  float*    fb    = (float*)(ws + WS_FB);
  _Float16* w2    = (_Float16*)(ws + WS_W2);
  _Float16* rtH   = (_Float16*)(ws + WS_RT);
  _Float16* whhH  = (_Float16*)(ws + WS_WHH);
  _Float16* wihH  = (_Float16*)(ws + WS_WIH);
  float*    swihT = (float*)(ws + WS_SWIHT);
  float*    swhhT = (float*)(ws + WS_SWHHT);
  float*    mwihT = (float*)(ws + WS_MWIHT);
  float*    l1wT  = (float*)(ws + WS_L1WT);
  float*    l2w   = (float*)(ws + WS_L2WF);

  switch (r) {
    case 0: fb[li] = v; break;          // lin0_w
    case 1: fb[192 + li] = v; break;    // lin0_b
    case 2: fb[256 + li] = v; break;    // e1_w
    case 3: fb[640 + li] = v; break;    // e1_b
    case 4: {                           // e2_w flat (i*64+o)*64+k -> tile i
      int i = li >> 12, o = (li >> 6) & 63, k = li & 63;
      w2[i * 4096 + (((k >> 3) * 64 + o) << 3) + (k & 7)] = (_Float16)v;
    } break;
    case 5: {                           // e2_b flat k*64+o -> tile 64
      int k = li >> 6, o = li & 63;
      w2[64 * 4096 + (((k >> 3) * 64 + o) << 3) + (k & 7)] = (_Float16)v;
    } break;
    case 6: {                           // root_w [i][o] -> rt[o*64+i]
      int i = li >> 6, o = li & 63;
      rtH[o * 64 + i] = (_Float16)v;
    } break;
    case 7: fb[704 + li] = v; break;    // conv_b
    case 8: wihH[li] = (_Float16)v; break;   // gru_wih [oo][i]
    case 9: whhH[li] = (_Float16)v; break;   // gru_whh [oo][i]
    case 10: fb[768 + li] = v; break;   // gru_bih
    case 11: fb[960 + li] = v; break;   // gru_bhh
    case 12: swihT[(li & 127) * 256 + (li >> 7)] = v; break;  // s2s_wih [256][128]
    case 13: swhhT[(li & 63) * 256 + (li >> 6)] = v; break;   // s2s_whh [256][64]
    case 14: fb[1152 + li] = v; break;  // s2s_bih
    case 15: fb[1408 + li] = v; break;  // s2s_bhh
    case 16: mwihT[(li & 127) * 256 + (li >> 7)] = v; break;  // mem_wih [256][128]
    case 17: fb[1664 + li] = v; break;  // mem_bih
    case 18: fb[1920 + li] = v; break;  // mem_bhh
    case 19: l1wT[(li % 320) * 64 + (li / 320)] = v; break;   // lin1_w [64][320]
    case 20: fb[2176 + li] = v; break;  // lin1_b
    case 21: l2w[li] = v; break;
    case 22: fb[2240 + li] = v; break;  // lin2_b
  }
}

// ---------------- node init: h = relu(x @ lin0_w.T + lin0_b), fp32 ----------------
__global__ __launch_bounds__(256) void init_kernel(
    const float* __restrict__ x, const float* __restrict__ fb,
    float* __restrict__ h) {
  int idx = blockIdx.x * 256 + threadIdx.x;  // n*64+o
  int n = idx >> 6, o = idx & 63;
  float acc = fb[192 + o];
#pragma unroll
  for (int j = 0; j < 3; j++) acc += x[n * 3 + j] * fb[o * 3 + j];
  h[idx] = fmaxf(acc, 0.f);
}

// ---------------- degree ----------------
__global__ __launch_bounds__(256) void deg_kernel(const int* __restrict__ edge_index,
                                                  float* __restrict__ deg) {
  int e = blockIdx.x * 256 + threadIdx.x;
  if (e < NEDGE) atomicAdd(&deg[edge_index[NEDGE + e]], 1.0f);
}

// ---------------- message GEMM, fp16; 128 edges/block, 2 A-tiles per wave ----------
// 256 threads = 4 waves; grid = 256. B fragments read once, used for 2 MFMAs.
__global__ __launch_bounds__(256) void msg_kernel(
    const float* __restrict__ h, const float* __restrict__ ea,
    const float* __restrict__ fb, const _Float16* __restrict__ w2,
    const int* __restrict__ edge_index, float* __restrict__ agg) {
  __shared__ _Float16 sOut[128][72];   // 18 KB
  __shared__ _Float16 sB[2][8192];     // 32 KB (2-tile phases, dbuf)
  const int tid = threadIdx.x;
  const int wave = tid >> 6, lane = tid & 63;
  const int m15 = lane & 15, quad = lane >> 4;
  const int eb = blockIdx.x * 128;
  {  // stage out[src] as fp16 for 128 edges (2 threads per row)
    int r = tid >> 1, c0 = (tid & 1) * 32;
    int srcn = edge_index[eb + r];
#pragma unroll
    for (int c = c0; c < c0 + 32; c += 4) {
      float4 v = *(const float4*)&h[srcn * D + c];
      sOut[r][c]     = (_Float16)v.x;
      sOut[r][c + 1] = (_Float16)v.y;
      sOut[r][c + 2] = (_Float16)v.z;
      sOut[r][c + 3] = (_Float16)v.w;
    }
  }
  const int erow1 = wave * 16 + m15;
  const int erow2 = 64 + erow1;
  const int e1 = eb + erow1, e2 = eb + erow2;
  // edge hidden (fp32 compute, fp16 store) for both edges, this lane's k-slices
  h8 hidA0, hidA1, hidB0, hidB1;
  {
    float eav1[6], eav2[6];
#pragma unroll
    for (int j = 0; j < 6; j++) { eav1[j] = ea[e1 * 6 + j]; eav2[j] = ea[e2 * 6 + j]; }
#pragma unroll
    for (int j = 0; j < 8; j++) {
      int k0 = quad * 8 + j, k1 = 32 + quad * 8 + j;
      float a01 = fb[640 + k0], a11 = fb[640 + k1];
      float a02 = a01, a12 = a11;
#pragma unroll
      for (int jj = 0; jj < 6; jj++) {
        float w0 = fb[256 + k0 * 6 + jj], w1 = fb[256 + k1 * 6 + jj];
        a01 += eav1[jj] * w0; a11 += eav1[jj] * w1;
        a02 += eav2[jj] * w0; a12 += eav2[jj] * w1;
      }
      hidA0[j] = (_Float16)fmaxf(a01, 0.f);
      hidA1[j] = (_Float16)fmaxf(a11, 0.f);
      hidB0[j] = (_Float16)fmaxf(a02, 0.f);
      hidB1[j] = (_Float16)fmaxf(a12, 0.f);
    }
  }
  // prefetch phase 0 (tiles 0,1): 16 chunks of 512 fp16
  for (int c = wave; c < 16; c += 4)
    gload_lds16(w2 + c * 512 + lane * 8, &sB[0][c * 512]);
  __syncthreads();
  f4 zz = {0.f, 0.f, 0.f, 0.f};
  f4 accA[4], accB[4];
#pragma unroll
  for (int nt = 0; nt < 4; nt++) { accA[nt] = zz; accB[nt] = zz; }
  for (int p = 0; p < 33; p++) {
    const int cur = p & 1;
    if (p < 32) {  // async prefetch next phase
      int nch = (p == 31) ? 8 : 16;
      const _Float16* src = w2 + (p + 1) * 8192;
      for (int c = wave; c < nch; c += 4)
        gload_lds16(src + c * 512 + lane * 8, &sB[cur ^ 1][c * 512]);
    }
    const int cnt = (p == 32) ? 1 : 2;
    for (int t = 0; t < cnt; t++) {
      const int i = p * 2 + t;
      h8 a10, a11, a20, a21;
      if (i < 64) {
        h8 o1 = splat16(sOut[erow1][i]);
        h8 o2 = splat16(sOut[erow2][i]);
        a10 = hidA0 * o1; a11 = hidA1 * o1;
        a20 = hidB0 * o2; a21 = hidB1 * o2;
      } else {  // bias tail: z = out_src
        a10 = *(const h8*)&sOut[erow1][quad * 8];
        a11 = *(const h8*)&sOut[erow1][32 + quad * 8];
        a20 = *(const h8*)&sOut[erow2][quad * 8];
        a21 = *(const h8*)&sOut[erow2][32 + quad * 8];
      }
      const _Float16* base = &sB[cur][t * 4096];
      const int q512 = quad * 512;
#pragma unroll
      for (int nt = 0; nt < 4; nt++) {
        int br8 = (nt * 16 + m15) * 8;
        h8 bh0 = *(const h8*)(base + q512 + br8);          // kc = quad
        h8 bh1 = *(const h8*)(base + 2048 + q512 + br8);   // kc = 4+quad
        accA[nt] = mfma16h(a10, bh0, accA[nt]);
        accA[nt] = mfma16h(a11, bh1, accA[nt]);
        accB[nt] = mfma16h(a20, bh0, accB[nt]);
        accB[nt] = mfma16h(a21, bh1, accB[nt]);
      }
    }
    __syncthreads();  // phase boundary: buffer reuse + prefetch completion
  }
#pragma unroll
  for (int reg = 0; reg < 4; reg++) {
    int r1 = eb + wave * 16 + quad * 4 + reg;
    int r2 = r1 + 64;
    int dn1 = edge_index[NEDGE + r1];
    int dn2 = edge_index[NEDGE + r2];
    float* ap1 = agg + dn1 * D;
    float* ap2 = agg + dn2 * D;
#pragma unroll
    for (int nt = 0; nt < 4; nt++) {
      atomicAdd(ap1 + nt * 16 + m15, accA[nt][reg]);
      atomicAdd(ap2 + nt * 16 + m15, accB[nt][reg]);
    }
  }
}

// ---------------- node update, fp16 MFMA; zeroes agg for the next iteration ----
__global__ __launch_bounds__(256) void update_kernel(
    float* __restrict__ h, float* __restrict__ agg, const float* __restrict__ deg,
    const _Float16* __restrict__ rtH, const _Float16* __restrict__ whhH,
    const _Float16* __restrict__ wihH, const float* __restrict__ fb) {
  __shared__ float buf[64][68];  // sH, then (after barrier) sM
  const int tid = threadIdx.x;
  const int wave = tid >> 6, lane = tid & 63;
  const int m15 = lane & 15, quad = lane >> 4;
  const int nb = blockIdx.x * 64;
  {
    int r = tid >> 2, c0 = (tid & 3) * 16;
#pragma unroll
    for (int c = c0; c < c0 + 16; c += 4)
      *(float4*)&buf[r][c] = *(const float4*)&h[(nb + r) * D + c];
  }
  __syncthreads();
  const int mrow = wave * 16 + m15;
  h8 a0, a1;
#pragma unroll
  for (int j = 0; j < 8; j++) {
    a0[j] = (_Float16)buf[mrow][quad * 8 + j];
    a1[j] = (_Float16)buf[mrow][32 + quad * 8 + j];
  }
  f4 zz = {0.f, 0.f, 0.f, 0.f};
  f4 acc[16];
#pragma unroll
  for (int nt = 0; nt < 16; nt++) acc[nt] = zz;
#pragma unroll
  for (int nt = 0; nt < 16; nt++) {
    int nn = nt * 16 + m15;
    const _Float16* bp = (nt < 4) ? (rtH + nn * D) : (whhH + (nn - 64) * D);
    h8 bh0 = *(const h8*)(bp + quad * 8);
    h8 bh1 = *(const h8*)(bp + 32 + quad * 8);
    f4 a = acc[nt];
    a = mfma16h(a0, bh0, a);
    a = mfma16h(a1, bh1, a);
    acc[nt] = a;
  }
  __syncthreads();  // everyone done reading sH
  // m = relu(root + agg/deg + conv_b), fp32, into buf; zero agg behind us
#pragma unroll
  for (int nt = 0; nt < 4; nt++) {
#pragma unroll
    for (int reg = 0; reg < 4; reg++) {
      int nloc = wave * 16 + quad * 4 + reg;
      int o = nt * 16 + m15;
      float dg = fmaxf(deg[nb + nloc], 1.f);
      int aidx = (nb + nloc) * D + o;
      float v = acc[nt][reg] + agg[aidx] / dg + fb[704 + o];
      agg[aidx] = 0.f;
      buf[nloc][o] = fmaxf(v, 0.f);
    }
  }
  __syncthreads();
  h8 m0, m1;
#pragma unroll
  for (int j = 0; j < 8; j++) {
    m0[j] = (_Float16)buf[mrow][quad * 8 + j];
    m1[j] = (_Float16)buf[mrow][32 + quad * 8 + j];
  }
  f4 g2[12];
#pragma unroll
  for (int nt = 0; nt < 12; nt++) g2[nt] = zz;
#pragma unroll
  for (int nt = 0; nt < 12; nt++) {
    int nn = nt * 16 + m15;
    const _Float16* bp = wihH + nn * D;
    h8 bh0 = *(const h8*)(bp + quad * 8);
    h8 bh1 = *(const h8*)(bp + 32 + quad * 8);
    f4 a = g2[nt];
    a = mfma16h(m0, bh0, a);
    a = mfma16h(m1, bh1, a);
    g2[nt] = a;
  }
#pragma unroll
  for (int nt = 0; nt < 4; nt++) {
#pragma unroll
    for (int reg = 0; reg < 4; reg++) {
      int nloc = wave * 16 + quad * 4 + reg;
      int o = nt * 16 + m15;
      int gidx = (nb + nloc) * D + o;
      float gir = g2[nt][reg]      + fb[768 + o];
      float giz = g2[nt + 4][reg]  + fb[768 + 64 + o];
      float gin = g2[nt + 8][reg]  + fb[768 + 128 + o];
      float ghr = acc[nt + 4][reg]  + fb[960 + o];
      float ghz = acc[nt + 8][reg]  + fb[960 + 64 + o];
      float ghn = acc[nt + 12][reg] + fb[960 + 128 + o];
      float rr = sigm(gir + ghr);
      float zg = sigm(giz + ghz);
      float nnv = tanhf(gin + rr * ghn);
      float hv = h[gidx];
      h[gidx] = (1.f - zg) * nnv + zg * hv;
    }
  }
}

// ---------------- fused Set2Set (6 steps) + memory LSTM; transposed weights ----
__global__ __launch_bounds__(256) void s2s_kernel(
    const float* __restrict__ h,
    const float* __restrict__ wihT, const float* __restrict__ whhT,
    const float* __restrict__ mwihT, const float* __restrict__ fb,
    float* __restrict__ hx_f32, float* __restrict__ dout) {
  __shared__ float outL[64][65];
  __shared__ float qs[128];
  __shared__ float hsv[64], csv[64], sg[256], sa[64];
  __shared__ float spart[4][64];
  const int t = threadIdx.x;
  const int g = blockIdx.x;
  for (int idx = t; idx < 64 * 64; idx += 256) outL[idx >> 6][idx & 63] = h[g * 4096 + idx];
  if (t < 128) qs[t] = 0.f;
  if (t < 64) { hsv[t] = 0.f; csv[t] = 0.f; }
  __syncthreads();
  for (int step = 0; step < 6; step++) {
    float acc = fb[1152 + t] + fb[1408 + t];
#pragma unroll 8
    for (int j = 0; j < 128; j++) acc += qs[j] * wihT[j * 256 + t];
#pragma unroll 8
    for (int j = 0; j < 64; j++) acc += hsv[j] * whhT[j * 256 + t];
    sg[t] = acc;
    __syncthreads();
    if (t < 64) {
      float cn = sigm(sg[64 + t]) * csv[t] + sigm(sg[t]) * tanhf(sg[128 + t]);
      csv[t] = cn;
      hsv[t] = sigm(sg[192 + t]) * tanhf(cn);
    }
    __syncthreads();
    if (t < 64) {
      float e = 0.f;
      for (int d2 = 0; d2 < 64; d2++) e += outL[t][d2] * hsv[d2];
      float mx = e;
      for (int off = 32; off > 0; off >>= 1) mx = fmaxf(mx, __shfl_xor(mx, off));
      float a = __expf(e - mx);
      float s = a;
      for (int off = 32; off > 0; off >>= 1) s += __shfl_xor(s, off);
      sa[t] = a / s;
    }
    __syncthreads();
    {
      int o = t & 63, part = t >> 6;
      float r = 0.f;
      for (int n2 = part * 16; n2 < part * 16 + 16; n2++) r += sa[n2] * outL[n2][o];
      spart[part][o] = r;
    }
    __syncthreads();
    if (t < 64) {
      qs[t] = hsv[t];
      qs[64 + t] = spart[0][t] + spart[1][t] + spart[2][t] + spart[3][t];
    }
    __syncthreads();
  }
  float acc = fb[1664 + t] + fb[1920 + t];
#pragma unroll 8
  for (int j = 0; j < 128; j++) acc += qs[j] * mwihT[j * 256 + t];
  sg[t] = acc;
  __syncthreads();
  if (t < 64) {
    float cn = sigm(sg[t]) * tanhf(sg[128 + t]);
    float hn = sigm(sg[192 + t]) * tanhf(cn);
    hx_f32[g * 64 + t] = hn;
    dout[TTOT * 6 + g * 64 + t] = hn;
    dout[TTOT * 6 + NG * 64 + g * 64 + t] = cn;
  }
}

// ---------------- head: faithful permute/reshape + lin1 + lin2; transposed l1w ----
__global__ __launch_bounds__(64) void head_kernel(
    const float* __restrict__ h, const float* __restrict__ hx_f32,
    const int* __restrict__ nonring, const int* __restrict__ nrbidx,
    const float* __restrict__ l1wT, const float* __restrict__ l2w,
    const float* __restrict__ fb, float* __restrict__ dout) {
  __shared__ float feat[320];
  __shared__ float so1[64];
  const int r = blockIdx.x;
  const int lane = threadIdx.x;
  const int blk = r % 48, di = r / 48;
  const int tt = blk * 64 + lane;
  feat[lane * 5] = hx_f32[nrbidx[tt] * 64 + di];
#pragma unroll
  for (int s = 1; s <= 4; s++)
    feat[lane * 5 + s] = h[nonring[(s - 1) * TTOT + tt] * 64 + di];
  __syncthreads();
  float acc = fb[2176 + lane];
#pragma unroll 8
  for (int c = 0; c < 320; c++) acc += feat[c] * l1wT[c * 64 + lane];
  so1[lane] = fmaxf(acc, 0.f);
  __syncthreads();
  if (lane < 6) {
    float a2 = fb[2240 + lane];
    for (int j = 0; j < 64; j++) a2 += so1[j] * l2w[lane * 64 + j];
    dout[r * 6 + lane] = a2;
  }
}

extern "C" void kernel_launch(void* const* d_in, const int* in_sizes, int n_in,
                              void* d_out, int out_size, void* d_ws, size_t ws_size,
                              hipStream_t stream) {
  (void)in_sizes; (void)n_in; (void)out_size;
  const float* x         = (const float*)d_in[0];
  const float* edge_attr = (const float*)d_in[1];
  const int* edge_index  = (const int*)d_in[2];
  const int* nonring     = (const int*)d_in[4];
  const int* nrbidx      = (const int*)d_in[5];
  float* out = (float*)d_out;

  char* ws = (char*)d_ws;
  float*    h      = (float*)(ws + WS_H);
  float*    agg    = (float*)(ws + WS_AGG);
  _Float16* w2     = (_Float16*)(ws + WS_W2);
  _Float16* rtH    = (_Float16*)(ws + WS_RT);
  _Float16* whhH   = (_Float16*)(ws + WS_WHH);
  _Float16* wihH   = (_Float16*)(ws + WS_WIH);
  float*    swihT  = (float*)(ws + WS_SWIHT);
  float*    swhhT  = (float*)(ws + WS_SWHHT);
  float*    mwihT  = (float*)(ws + WS_MWIHT);
  float*    l1wT   = (float*)(ws + WS_L1WT);
  float*    l2wF   = (float*)(ws + WS_L2WF);
  float*    fb     = (float*)(ws + WS_FB);
  float*    deg    = (float*)(ws + WS_DEG);
  float*    hx_f32 = (float*)(ws + WS_HX);
  if (ws_size < (size_t)WS_NEED) return;

  Srcs S;
  S.p[0] = d_in[8];   S.p[1] = d_in[9];   S.p[2] = d_in[10];  S.p[3] = d_in[11];
  S.p[4] = d_in[12];  S.p[5] = d_in[13];  S.p[6] = d_in[14];  S.p[7] = d_in[15];
  S.p[8] = d_in[16];  S.p[9] = d_in[17];  S.p[10] = d_in[18]; S.p[11] = d_in[19];
  S.p[12] = d_in[20]; S.p[13] = d_in[21]; S.p[14] = d_in[22]; S.p[15] = d_in[23];
  S.p[16] = d_in[24]; S.p[17] = d_in[26]; S.p[18] = d_in[27]; S.p[19] = d_in[28];
  S.p[20] = d_in[29]; S.p[21] = d_in[30]; S.p[22] = d_in[31];
  pack_kernel<<<(399942 + 255) / 256, 256, 0, stream>>>(S, ws);

  init_kernel<<<NNODE * D / 256, 256, 0, stream>>>(x, fb, h);
  hipMemsetAsync(deg, 0, NNODE * 4, stream);
  hipMemsetAsync(agg, 0, NNODE * D * 4, stream);
  deg_kernel<<<NEDGE / 256, 256, 0, stream>>>(edge_index, deg);

  for (int it = 0; it < 6; it++) {
    msg_kernel<<<NEDGE / 128, 256, 0, stream>>>(h, edge_attr, fb, w2, edge_index, agg);
    update_kernel<<<NNODE / 64, 256, 0, stream>>>(h, agg, deg, rtH, whhH, wihH, fb);
  }

  s2s_kernel<<<NG, 256, 0, stream>>>(h, swihT, swhhT, mwihT, fb, hx_f32, out);
  head_kernel<<<TTOT, 64, 0, stream>>>(h, hx_f32, nonring, nrbidx, l1wT, l2wF, fb, out);
}

// Round 9
// 498.595 us; speedup vs baseline: 1.5996x; 1.0635x over previous
//
#include <hip/hip_runtime.h>

#define NNODE 16384
#define NEDGE 32768
#define NG    256
#define TPGx  12
#define TTOT  (NG * TPGx)   // 3072
#define D     64

typedef _Float16 h8 __attribute__((ext_vector_type(8)));
typedef float    f4 __attribute__((ext_vector_type(4)));

static __device__ __forceinline__ float sigm(float x) { return 1.f / (1.f + __expf(-x)); }

static __device__ __forceinline__ f4 mfma16h(h8 a, h8 b, f4 c) {
  return __builtin_amdgcn_mfma_f32_16x16x32_f16(a, b, c, 0, 0, 0);
}

static __device__ __forceinline__ h8 splat16(_Float16 x) {
  h8 v = {x, x, x, x, x, x, x, x};
  return v;
}

// async global->LDS, 16B per lane; lds base wave-uniform (HW adds lane*16)
static __device__ __forceinline__ void gload_lds16(const void* g, void* l) {
  __builtin_amdgcn_global_load_lds(
      (const __attribute__((address_space(1))) unsigned int*)g,
      (__attribute__((address_space(3))) unsigned int*)l, 16, 0, 0);
}

// ---------------- workspace layout (byte offsets) ----------------
#define WS_H      0          // float [N*64]   4 MiB
#define WS_AGG    4194304    // float [N*64]   4 MiB
#define WS_W2     8388608    // fp16 [65 tiles * 4096]; tile i idx=((k>>3)*64+o)*8+(k&7)
#define WS_RT     8921088    // fp16 [64*64]  rt[o][i]
#define WS_WHH    8929280    // fp16 [192*64] natural [oo][i]
#define WS_WIH    8953856    // fp16 [192*64]
#define WS_SWIHT  8978432    // f32 [128][256] transposed
#define WS_SWHHT  9109504    // f32 [64][256]  transposed
#define WS_MWIHT  9175040    // f32 [128][256] transposed
#define WS_L1WT   9306112    // f32 [320][64]  transposed
#define WS_L2WF   9388032    // f32 [6*64]
#define WS_FB     9389568    // f32 [2246]
#define WS_DEG    9398784    // f32 [N]
#define WS_HX     9464320    // f32 [G*64]
#define WS_NEED   9529856
// fb sub-offsets (floats): lin0w 0, lin0b 192, e1w 256, e1b 640, convb 704,
// gbih 768, gbhh 960, s2sbih 1152, s2sbhh 1408, membih 1664, membhh 1920,
// l1b 2176, l2b 2240

// ---------------- pack fp32 params; GEMM weights -> fp16; s2s/head transposed ------
struct Srcs { const void* p[23]; };

__device__ __constant__ const int kCum[24] = {
    0, 192, 256, 640, 704, 262848, 266944, 271040, 271104, 283392, 295680,
    295872, 296064, 328832, 345216, 345472, 345728, 378496, 378752, 379008,
    399488, 399552, 399936, 399942};

__global__ __launch_bounds__(256) void pack_kernel(Srcs S, char* __restrict__ ws) {
  int idx = blockIdx.x * 256 + threadIdx.x;
  if (idx >= 399942) return;
  int r = 0, base = 0;
#pragma unroll
  for (int k = 0; k < 23; k++)
    if (idx >= kCum[k]) { r = k; base = kCum[k]; }
  int li = idx - base;
  float v = ((const float*)S.p[r])[li];

  float*    fb    = (float*)(ws + WS_FB);
  _Float16* w2    = (_Float16*)(ws + WS_W2);
  _Float16* rtH   = (_Float16*)(ws + WS_RT);
  _Float16* whhH  = (_Float16*)(ws + WS_WHH);
  _Float16* wihH  = (_Float16*)(ws + WS_WIH);
  float*    swihT = (float*)(ws + WS_SWIHT);
  float*    swhhT = (float*)(ws + WS_SWHHT);
  float*    mwihT = (float*)(ws + WS_MWIHT);
  float*    l1wT  = (float*)(ws + WS_L1WT);
  float*    l2w   = (float*)(ws + WS_L2WF);

  switch (r) {
    case 0: fb[li] = v; break;          // lin0_w
    case 1: fb[192 + li] = v; break;    // lin0_b
    case 2: fb[256 + li] = v; break;    // e1_w
    case 3: fb[640 + li] = v; break;    // e1_b
    case 4: {                           // e2_w flat (i*64+o)*64+k -> tile i
      int i = li >> 12, o = (li >> 6) & 63, k = li & 63;
      w2[i * 4096 + (((k >> 3) * 64 + o) << 3) + (k & 7)] = (_Float16)v;
    } break;
    case 5: {                           // e2_b flat k*64+o -> tile 64
      int k = li >> 6, o = li & 63;
      w2[64 * 4096 + (((k >> 3) * 64 + o) << 3) + (k & 7)] = (_Float16)v;
    } break;
    case 6: {                           // root_w [i][o] -> rt[o*64+i]
      int i = li >> 6, o = li & 63;
      rtH[o * 64 + i] = (_Float16)v;
    } break;
    case 7: fb[704 + li] = v; break;    // conv_b
    case 8: wihH[li] = (_Float16)v; break;   // gru_wih [oo][i]
    case 9: whhH[li] = (_Float16)v; break;   // gru_whh [oo][i]
    case 10: fb[768 + li] = v; break;   // gru_bih
    case 11: fb[960 + li] = v; break;   // gru_bhh
    case 12: swihT[(li & 127) * 256 + (li >> 7)] = v; break;  // s2s_wih [256][128]
    case 13: swhhT[(li & 63) * 256 + (li >> 6)] = v; break;   // s2s_whh [256][64]
    case 14: fb[1152 + li] = v; break;  // s2s_bih
    case 15: fb[1408 + li] = v; break;  // s2s_bhh
    case 16: mwihT[(li & 127) * 256 + (li >> 7)] = v; break;  // mem_wih [256][128]
    case 17: fb[1664 + li] = v; break;  // mem_bih
    case 18: fb[1920 + li] = v; break;  // mem_bhh
    case 19: l1wT[(li % 320) * 64 + (li / 320)] = v; break;   // lin1_w [64][320]
    case 20: fb[2176 + li] = v; break;  // lin1_b
    case 21: l2w[li] = v; break;
    case 22: fb[2240 + li] = v; break;  // lin2_b
  }
}

// ---------------- node init: h = relu(x @ lin0_w.T + lin0_b), fp32 ----------------
__global__ __launch_bounds__(256) void init_kernel(
    const float* __restrict__ x, const float* __restrict__ fb,
    float* __restrict__ h) {
  int idx = blockIdx.x * 256 + threadIdx.x;  // n*64+o
  int n = idx >> 6, o = idx & 63;
  float acc = fb[192 + o];
#pragma unroll
  for (int j = 0; j < 3; j++) acc += x[n * 3 + j] * fb[o * 3 + j];
  h[idx] = fmaxf(acc, 0.f);
}

// ---------------- degree ----------------
__global__ __launch_bounds__(256) void deg_kernel(const int* __restrict__ edge_index,
                                                  float* __restrict__ deg) {
  int e = blockIdx.x * 256 + threadIdx.x;
  if (e < NEDGE) atomicAdd(&deg[edge_index[NEDGE + e]], 1.0f);
}

// ---------------- message GEMM, fp16; 64 edges/block, wave = 32 edges x 32 cols ----
// 256 threads = 4 waves; grid = 512 (2 blocks/CU). B fragment feeds 2 edge-tiles.
__global__ __launch_bounds__(256) void msg_kernel(
    const float* __restrict__ h, const float* __restrict__ ea,
    const float* __restrict__ fb, const _Float16* __restrict__ w2,
    const int* __restrict__ edge_index, float* __restrict__ agg) {
  __shared__ _Float16 sOut[64][72];    // 9 KB
  __shared__ _Float16 sB[2][16384];    // 64 KB (4-tile phases, dbuf)
  const int tid = threadIdx.x;
  const int wave = tid >> 6, lane = tid & 63;
  const int m15 = lane & 15, quad = lane >> 4;
  const int eg = wave >> 1;   // edge half (0/1): erow tiles {2eg, 2eg+1}
  const int cg = wave & 1;    // col half (0/1): nt in {2cg, 2cg+1}
  const int eb = blockIdx.x * 64;
  {  // stage out[src] as fp16 for 64 edges
    int r = tid >> 2, c0 = (tid & 3) * 16;
    int srcn = edge_index[eb + r];
#pragma unroll
    for (int c = c0; c < c0 + 16; c += 4) {
      float4 v = *(const float4*)&h[srcn * D + c];
      sOut[r][c]     = (_Float16)v.x;
      sOut[r][c + 1] = (_Float16)v.y;
      sOut[r][c + 2] = (_Float16)v.z;
      sOut[r][c + 3] = (_Float16)v.w;
    }
  }
  const int erowA = eg * 32 + m15;
  const int erowB = erowA + 16;
  const int e1 = eb + erowA, e2 = eb + erowB;
  // edge hidden (fp32 compute, fp16 store) for both edges, this lane's k-slices
  h8 hidA0, hidA1, hidB0, hidB1;
  {
    float eav1[6], eav2[6];
#pragma unroll
    for (int j = 0; j < 6; j++) { eav1[j] = ea[e1 * 6 + j]; eav2[j] = ea[e2 * 6 + j]; }
#pragma unroll
    for (int j = 0; j < 8; j++) {
      int k0 = quad * 8 + j, k1 = 32 + quad * 8 + j;
      float a01 = fb[640 + k0], a11 = fb[640 + k1];
      float a02 = a01, a12 = a11;
#pragma unroll
      for (int jj = 0; jj < 6; jj++) {
        float w0 = fb[256 + k0 * 6 + jj], w1 = fb[256 + k1 * 6 + jj];
        a01 += eav1[jj] * w0; a11 += eav1[jj] * w1;
        a02 += eav2[jj] * w0; a12 += eav2[jj] * w1;
      }
      hidA0[j] = (_Float16)fmaxf(a01, 0.f);
      hidA1[j] = (_Float16)fmaxf(a11, 0.f);
      hidB0[j] = (_Float16)fmaxf(a02, 0.f);
      hidB1[j] = (_Float16)fmaxf(a12, 0.f);
    }
  }
  // prefetch phase 0 (tiles 0..3): 32 chunks of 512 fp16
  for (int c = wave; c < 32; c += 4)
    gload_lds16(w2 + c * 512 + lane * 8, &sB[0][c * 512]);
  __syncthreads();
  f4 zz = {0.f, 0.f, 0.f, 0.f};
  f4 accA[2], accB[2];
#pragma unroll
  for (int j = 0; j < 2; j++) { accA[j] = zz; accB[j] = zz; }
  for (int p = 0; p < 17; p++) {
    const int cur = p & 1;
    if (p < 16) {  // async prefetch next phase
      int nch = (p == 15) ? 8 : 32;  // last phase has 1 tile
      const _Float16* src = w2 + (p + 1) * 16384;
      for (int c = wave; c < nch; c += 4)
        gload_lds16(src + c * 512 + lane * 8, &sB[cur ^ 1][c * 512]);
    }
    const int cnt = (p == 16) ? 1 : 4;
    for (int t = 0; t < cnt; t++) {
      const int i = p * 4 + t;
      h8 a10, a11, a20, a21;
      if (i < 64) {
        h8 o1 = splat16(sOut[erowA][i]);
        h8 o2 = splat16(sOut[erowB][i]);
        a10 = hidA0 * o1; a11 = hidA1 * o1;
        a20 = hidB0 * o2; a21 = hidB1 * o2;
      } else {  // bias tail: z = out_src
        a10 = *(const h8*)&sOut[erowA][quad * 8];
        a11 = *(const h8*)&sOut[erowA][32 + quad * 8];
        a20 = *(const h8*)&sOut[erowB][quad * 8];
        a21 = *(const h8*)&sOut[erowB][32 + quad * 8];
      }
      const _Float16* base = &sB[cur][t * 4096];
      const int q512 = quad * 512;
#pragma unroll
      for (int j = 0; j < 2; j++) {
        int nt = cg * 2 + j;
        int br8 = (nt * 16 + m15) * 8;
        h8 bh0 = *(const h8*)(base + q512 + br8);          // kc = quad
        h8 bh1 = *(const h8*)(base + 2048 + q512 + br8);   // kc = 4+quad
        accA[j] = mfma16h(a10, bh0, accA[j]);
        accA[j] = mfma16h(a11, bh1, accA[j]);
        accB[j] = mfma16h(a20, bh0, accB[j]);
        accB[j] = mfma16h(a21, bh1, accB[j]);
      }
    }
    __syncthreads();  // phase boundary: buffer reuse + prefetch completion
  }
#pragma unroll
  for (int reg = 0; reg < 4; reg++) {
    int rA = eb + eg * 32 + quad * 4 + reg;
    int rB = rA + 16;
    int dnA = edge_index[NEDGE + rA];
    int dnB = edge_index[NEDGE + rB];
#pragma unroll
    for (int j = 0; j < 2; j++) {
      int o = (cg * 2 + j) * 16 + m15;
      atomicAdd(agg + dnA * D + o, accA[j][reg]);
      atomicAdd(agg + dnB * D + o, accB[j][reg]);
    }
  }
}

// ---------------- node update, fp16 MFMA; zeroes agg for the next iteration ----
__global__ __launch_bounds__(256) void update_kernel(
    float* __restrict__ h, float* __restrict__ agg, const float* __restrict__ deg,
    const _Float16* __restrict__ rtH, const _Float16* __restrict__ whhH,
    const _Float16* __restrict__ wihH, const float* __restrict__ fb) {
  __shared__ float buf[64][68];  // sH, then (after barrier) sM
  const int tid = threadIdx.x;
  const int wave = tid >> 6, lane = tid & 63;
  const int m15 = lane & 15, quad = lane >> 4;
  const int nb = blockIdx.x * 64;
  {
    int r = tid >> 2, c0 = (tid & 3) * 16;
#pragma unroll
    for (int c = c0; c < c0 + 16; c += 4)
      *(float4*)&buf[r][c] = *(const float4*)&h[(nb + r) * D + c];
  }
  __syncthreads();
  const int mrow = wave * 16 + m15;
  h8 a0, a1;
#pragma unroll
  for (int j = 0; j < 8; j++) {
    a0[j] = (_Float16)buf[mrow][quad * 8 + j];
    a1[j] = (_Float16)buf[mrow][32 + quad * 8 + j];
  }
  f4 zz = {0.f, 0.f, 0.f, 0.f};
  f4 acc[16];
#pragma unroll
  for (int nt = 0; nt < 16; nt++) acc[nt] = zz;
#pragma unroll
  for (int nt = 0; nt < 16; nt++) {
    int nn = nt * 16 + m15;
    const _Float16* bp = (nt < 4) ? (rtH + nn * D) : (whhH + (nn - 64) * D);
    h8 bh0 = *(const h8*)(bp + quad * 8);
    h8 bh1 = *(const h8*)(bp + 32 + quad * 8);
    f4 a = acc[nt];
    a = mfma16h(a0, bh0, a);
    a = mfma16h(a1, bh1, a);
    acc[nt] = a;
  }
  __syncthreads();  // everyone done reading sH
  // m = relu(root + agg/deg + conv_b), fp32, into buf; zero agg behind us
#pragma unroll
  for (int nt = 0; nt < 4; nt++) {
#pragma unroll
    for (int reg = 0; reg < 4; reg++) {
      int nloc = wave * 16 + quad * 4 + reg;
      int o = nt * 16 + m15;
      float dg = fmaxf(deg[nb + nloc], 1.f);
      int aidx = (nb + nloc) * D + o;
      float v = acc[nt][reg] + agg[aidx] / dg + fb[704 + o];
      agg[aidx] = 0.f;
      buf[nloc][o] = fmaxf(v, 0.f);
    }
  }
  __syncthreads();
  h8 m0, m1;
#pragma unroll
  for (int j = 0; j < 8; j++) {
    m0[j] = (_Float16)buf[mrow][quad * 8 + j];
    m1[j] = (_Float16)buf[mrow][32 + quad * 8 + j];
  }
  f4 g2[12];
#pragma unroll
  for (int nt = 0; nt < 12; nt++) g2[nt] = zz;
#pragma unroll
  for (int nt = 0; nt < 12; nt++) {
    int nn = nt * 16 + m15;
    const _Float16* bp = wihH + nn * D;
    h8 bh0 = *(const h8*)(bp + quad * 8);
    h8 bh1 = *(const h8*)(bp + 32 + quad * 8);
    f4 a = g2[nt];
    a = mfma16h(m0, bh0, a);
    a = mfma16h(m1, bh1, a);
    g2[nt] = a;
  }
#pragma unroll
  for (int nt = 0; nt < 4; nt++) {
#pragma unroll
    for (int reg = 0; reg < 4; reg++) {
      int nloc = wave * 16 + quad * 4 + reg;
      int o = nt * 16 + m15;
      int gidx = (nb + nloc) * D + o;
      float gir = g2[nt][reg]      + fb[768 + o];
      float giz = g2[nt + 4][reg]  + fb[768 + 64 + o];
      float gin = g2[nt + 8][reg]  + fb[768 + 128 + o];
      float ghr = acc[nt + 4][reg]  + fb[960 + o];
      float ghz = acc[nt + 8][reg]  + fb[960 + 64 + o];
      float ghn = acc[nt + 12][reg] + fb[960 + 128 + o];
      float rr = sigm(gir + ghr);
      float zg = sigm(giz + ghz);
      float nnv = tanhf(gin + rr * ghn);
      float hv = h[gidx];
      h[gidx] = (1.f - zg) * nnv + zg * hv;
    }
  }
}

// ---------------- fused Set2Set (6 steps) + memory LSTM; transposed weights ----
__global__ __launch_bounds__(256) void s2s_kernel(
    const float* __restrict__ h,
    const float* __restrict__ wihT, const float* __restrict__ whhT,
    const float* __restrict__ mwihT, const float* __restrict__ fb,
    float* __restrict__ hx_f32, float* __restrict__ dout) {
  __shared__ float outL[64][65];
  __shared__ float qs[128];
  __shared__ float hsv[64], csv[64], sg[256], sa[64];
  __shared__ float spart[4][64];
  const int t = threadIdx.x;
  const int g = blockIdx.x;
  for (int idx = t; idx < 64 * 64; idx += 256) outL[idx >> 6][idx & 63] = h[g * 4096 + idx];
  if (t < 128) qs[t] = 0.f;
  if (t < 64) { hsv[t] = 0.f; csv[t] = 0.f; }
  __syncthreads();
  for (int step = 0; step < 6; step++) {
    float acc = fb[1152 + t] + fb[1408 + t];
#pragma unroll 8
    for (int j = 0; j < 128; j++) acc += qs[j] * wihT[j * 256 + t];
#pragma unroll 8
    for (int j = 0; j < 64; j++) acc += hsv[j] * whhT[j * 256 + t];
    sg[t] = acc;
    __syncthreads();
    if (t < 64) {
      float cn = sigm(sg[64 + t]) * csv[t] + sigm(sg[t]) * tanhf(sg[128 + t]);
      csv[t] = cn;
      hsv[t] = sigm(sg[192 + t]) * tanhf(cn);
    }
    __syncthreads();
    if (t < 64) {
      float e = 0.f;
      for (int d2 = 0; d2 < 64; d2++) e += outL[t][d2] * hsv[d2];
      float mx = e;
      for (int off = 32; off > 0; off >>= 1) mx = fmaxf(mx, __shfl_xor(mx, off));
      float a = __expf(e - mx);
      float s = a;
      for (int off = 32; off > 0; off >>= 1) s += __shfl_xor(s, off);
      sa[t] = a / s;
    }
    __syncthreads();
    {
      int o = t & 63, part = t >> 6;
      float r = 0.f;
      for (int n2 = part * 16; n2 < part * 16 + 16; n2++) r += sa[n2] * outL[n2][o];
      spart[part][o] = r;
    }
    __syncthreads();
    if (t < 64) {
      qs[t] = hsv[t];
      qs[64 + t] = spart[0][t] + spart[1][t] + spart[2][t] + spart[3][t];
    }
    __syncthreads();
  }
  float acc = fb[1664 + t] + fb[1920 + t];
#pragma unroll 8
  for (int j = 0; j < 128; j++) acc += qs[j] * mwihT[j * 256 + t];
  sg[t] = acc;
  __syncthreads();
  if (t < 64) {
    float cn = sigm(sg[t]) * tanhf(sg[128 + t]);
    float hn = sigm(sg[192 + t]) * tanhf(cn);
    hx_f32[g * 64 + t] = hn;
    dout[TTOT * 6 + g * 64 + t] = hn;
    dout[TTOT * 6 + NG * 64 + g * 64 + t] = cn;
  }
}

// ---------------- head: faithful permute/reshape + lin1 + lin2; transposed l1w ----
__global__ __launch_bounds__(64) void head_kernel(
    const float* __restrict__ h, const float* __restrict__ hx_f32,
    const int* __restrict__ nonring, const int* __restrict__ nrbidx,
    const float* __restrict__ l1wT, const float* __restrict__ l2w,
    const float* __restrict__ fb, float* __restrict__ dout) {
  __shared__ float feat[320];
  __shared__ float so1[64];
  const int r = blockIdx.x;
  const int lane = threadIdx.x;
  const int blk = r % 48, di = r / 48;
  const int tt = blk * 64 + lane;
  feat[lane * 5] = hx_f32[nrbidx[tt] * 64 + di];
#pragma unroll
  for (int s = 1; s <= 4; s++)
    feat[lane * 5 + s] = h[nonring[(s - 1) * TTOT + tt] * 64 + di];
  __syncthreads();
  float acc = fb[2176 + lane];
#pragma unroll 8
  for (int c = 0; c < 320; c++) acc += feat[c] * l1wT[c * 64 + lane];
  so1[lane] = fmaxf(acc, 0.f);
  __syncthreads();
  if (lane < 6) {
    float a2 = fb[2240 + lane];
    for (int j = 0; j < 64; j++) a2 += so1[j] * l2w[lane * 64 + j];
    dout[r * 6 + lane] = a2;
  }
}

extern "C" void kernel_launch(void* const* d_in, const int* in_sizes, int n_in,
                              void* d_out, int out_size, void* d_ws, size_t ws_size,
                              hipStream_t stream) {
  (void)in_sizes; (void)n_in; (void)out_size;
  const float* x         = (const float*)d_in[0];
  const float* edge_attr = (const float*)d_in[1];
  const int* edge_index  = (const int*)d_in[2];
  const int* nonring     = (const int*)d_in[4];
  const int* nrbidx      = (const int*)d_in[5];
  float* out = (float*)d_out;

  char* ws = (char*)d_ws;
  float*    h      = (float*)(ws + WS_H);
  float*    agg    = (float*)(ws + WS_AGG);
  _Float16* w2     = (_Float16*)(ws + WS_W2);
  _Float16* rtH    = (_Float16*)(ws + WS_RT);
  _Float16* whhH   = (_Float16*)(ws + WS_WHH);
  _Float16* wihH   = (_Float16*)(ws + WS_WIH);
  float*    swihT  = (float*)(ws + WS_SWIHT);
  float*    swhhT  = (float*)(ws + WS_SWHHT);
  float*    mwihT  = (float*)(ws + WS_MWIHT);
  float*    l1wT   = (float*)(ws + WS_L1WT);
  float*    l2wF   = (float*)(ws + WS_L2WF);
  float*    fb     = (float*)(ws + WS_FB);
  float*    deg    = (float*)(ws + WS_DEG);
  float*    hx_f32 = (float*)(ws + WS_HX);
  if (ws_size < (size_t)WS_NEED) return;

  Srcs S;
  S.p[0] = d_in[8];   S.p[1] = d_in[9];   S.p[2] = d_in[10];  S.p[3] = d_in[11];
  S.p[4] = d_in[12];  S.p[5] = d_in[13];  S.p[6] = d_in[14];  S.p[7] = d_in[15];
  S.p[8] = d_in[16];  S.p[9] = d_in[17];  S.p[10] = d_in[18]; S.p[11] = d_in[19];
  S.p[12] = d_in[20]; S.p[13] = d_in[21]; S.p[14] = d_in[22]; S.p[15] = d_in[23];
  S.p[16] = d_in[24]; S.p[17] = d_in[26]; S.p[18] = d_in[27]; S.p[19] = d_in[28];
  S.p[20] = d_in[29]; S.p[21] = d_in[30]; S.p[22] = d_in[31];
  pack_kernel<<<(399942 + 255) / 256, 256, 0, stream>>>(S, ws);

  init_kernel<<<NNODE * D / 256, 256, 0, stream>>>(x, fb, h);
  hipMemsetAsync(deg, 0, NNODE * 4, stream);
  hipMemsetAsync(agg, 0, NNODE * D * 4, stream);
  deg_kernel<<<NEDGE / 256, 256, 0, stream>>>(edge_index, deg);

  for (int it = 0; it < 6; it++) {
    msg_kernel<<<NEDGE / 64, 256, 0, stream>>>(h, edge_attr, fb, w2, edge_index, agg);
    update_kernel<<<NNODE / 64, 256, 0, stream>>>(h, agg, deg, rtH, whhH, wihH, fb);
  }

  s2s_kernel<<<NG, 256, 0, stream>>>(h, swihT, swhhT, mwihT, fb, hx_f32, out);
  head_kernel<<<TTOT, 64, 0, stream>>>(h, hx_f32, nonring, nrbidx, l1wT, l2wF, fb, out);
}

// Round 10
// 443.380 us; speedup vs baseline: 1.7988x; 1.1245x over previous
//
#include <hip/hip_runtime.h>

#define NNODE 16384
#define NEDGE 32768
#define NG    256
#define TPGx  12
#define TTOT  (NG * TPGx)   // 3072
#define D     64

typedef _Float16 h8 __attribute__((ext_vector_type(8)));
typedef _Float16 h4 __attribute__((ext_vector_type(4)));
typedef float    f4 __attribute__((ext_vector_type(4)));

static __device__ __forceinline__ float sigm(float x) { return 1.f / (1.f + __expf(-x)); }

static __device__ __forceinline__ f4 mfma16h(h8 a, h8 b, f4 c) {
  return __builtin_amdgcn_mfma_f32_16x16x32_f16(a, b, c, 0, 0, 0);
}

static __device__ __forceinline__ h8 splat16(_Float16 x) {
  h8 v = {x, x, x, x, x, x, x, x};
  return v;
}

// ---------------- workspace layout (byte offsets) ----------------
#define WS_H      0          // float [N*64]   4 MiB
#define WS_AGG    4194304    // float [N*64]   4 MiB
#define WS_W2     8388608    // fp16 [65 tiles * 4096]; tile i idx=((k>>3)*64+o)*8+(k&7)
#define WS_RT     8921088    // fp16 [64*64]  rt[o][i]
#define WS_WHH    8929280    // fp16 [192*64] natural [oo][i]
#define WS_WIH    8953856    // fp16 [192*64]
#define WS_SWIHT  8978432    // f32 [128][256] transposed
#define WS_SWHHT  9109504    // f32 [64][256]  transposed
#define WS_MWIHT  9175040    // f32 [128][256] transposed
#define WS_L1WT   9306112    // f32 [320][64]  transposed
#define WS_L2WF   9388032    // f32 [6*64]
#define WS_FB     9389568    // f32 [2246]
#define WS_DEG    9398784    // f32 [N]
#define WS_HX     9464320    // f32 [G*64]
#define WS_NEED   9529856
// fb sub-offsets (floats): lin0w 0, lin0b 192, e1w 256, e1b 640, convb 704,
// gbih 768, gbhh 960, s2sbih 1152, s2sbhh 1408, membih 1664, membhh 1920,
// l1b 2176, l2b 2240

// ---------------- pack fp32 params; GEMM weights -> fp16; s2s/head transposed ------
struct Srcs { const void* p[23]; };

__device__ __constant__ const int kCum[24] = {
    0, 192, 256, 640, 704, 262848, 266944, 271040, 271104, 283392, 295680,
    295872, 296064, 328832, 345216, 345472, 345728, 378496, 378752, 379008,
    399488, 399552, 399936, 399942};

__global__ __launch_bounds__(256) void pack_kernel(Srcs S, char* __restrict__ ws) {
  int idx = blockIdx.x * 256 + threadIdx.x;
  if (idx >= 399942) return;
  int r = 0, base = 0;
#pragma unroll
  for (int k = 0; k < 23; k++)
    if (idx >= kCum[k]) { r = k; base = kCum[k]; }
  int li = idx - base;
  float v = ((const float*)S.p[r])[li];

  float*    fb    = (float*)(ws + WS_FB);
  _Float16* w2    = (_Float16*)(ws + WS_W2);
  _Float16* rtH   = (_Float16*)(ws + WS_RT);
  _Float16* whhH  = (_Float16*)(ws + WS_WHH);
  _Float16* wihH  = (_Float16*)(ws + WS_WIH);
  float*    swihT = (float*)(ws + WS_SWIHT);
  float*    swhhT = (float*)(ws + WS_SWHHT);
  float*    mwihT = (float*)(ws + WS_MWIHT);
  float*    l1wT  = (float*)(ws + WS_L1WT);
  float*    l2w   = (float*)(ws + WS_L2WF);

  switch (r) {
    case 0: fb[li] = v; break;          // lin0_w
    case 1: fb[192 + li] = v; break;    // lin0_b
    case 2: fb[256 + li] = v; break;    // e1_w
    case 3: fb[640 + li] = v; break;    // e1_b
    case 4: {                           // e2_w flat (i*64+o)*64+k -> tile i
      int i = li >> 12, o = (li >> 6) & 63, k = li & 63;
      w2[i * 4096 + (((k >> 3) * 64 + o) << 3) + (k & 7)] = (_Float16)v;
    } break;
    case 5: {                           // e2_b flat k*64+o -> tile 64
      int k = li >> 6, o = li & 63;
      w2[64 * 4096 + (((k >> 3) * 64 + o) << 3) + (k & 7)] = (_Float16)v;
    } break;
    case 6: {                           // root_w [i][o] -> rt[o*64+i]
      int i = li >> 6, o = li & 63;
      rtH[o * 64 + i] = (_Float16)v;
    } break;
    case 7: fb[704 + li] = v; break;    // conv_b
    case 8: wihH[li] = (_Float16)v; break;   // gru_wih [oo][i]
    case 9: whhH[li] = (_Float16)v; break;   // gru_whh [oo][i]
    case 10: fb[768 + li] = v; break;   // gru_bih
    case 11: fb[960 + li] = v; break;   // gru_bhh
    case 12: swihT[(li & 127) * 256 + (li >> 7)] = v; break;  // s2s_wih [256][128]
    case 13: swhhT[(li & 63) * 256 + (li >> 6)] = v; break;   // s2s_whh [256][64]
    case 14: fb[1152 + li] = v; break;  // s2s_bih
    case 15: fb[1408 + li] = v; break;  // s2s_bhh
    case 16: mwihT[(li & 127) * 256 + (li >> 7)] = v; break;  // mem_wih [256][128]
    case 17: fb[1664 + li] = v; break;  // mem_bih
    case 18: fb[1920 + li] = v; break;  // mem_bhh
    case 19: l1wT[(li % 320) * 64 + (li / 320)] = v; break;   // lin1_w [64][320]
    case 20: fb[2176 + li] = v; break;  // lin1_b
    case 21: l2w[li] = v; break;
    case 22: fb[2240 + li] = v; break;  // lin2_b
  }
}

// ---------------- node init: h = relu(x @ lin0_w.T + lin0_b), fp32 ----------------
__global__ __launch_bounds__(256) void init_kernel(
    const float* __restrict__ x, const float* __restrict__ fb,
    float* __restrict__ h) {
  int idx = blockIdx.x * 256 + threadIdx.x;  // n*64+o
  int n = idx >> 6, o = idx & 63;
  float acc = fb[192 + o];
#pragma unroll
  for (int j = 0; j < 3; j++) acc += x[n * 3 + j] * fb[o * 3 + j];
  h[idx] = fmaxf(acc, 0.f);
}

// ---------------- degree ----------------
__global__ __launch_bounds__(256) void deg_kernel(const int* __restrict__ edge_index,
                                                  float* __restrict__ deg) {
  int e = blockIdx.x * 256 + threadIdx.x;
  if (e < NEDGE) atomicAdd(&deg[edge_index[NEDGE + e]], 1.0f);
}

// ---------------- message GEMM, fp16; register-streamed B (no LDS staging) --------
// 256 threads = 4 waves; 64 edges/block; wave = 64 edges x 16 cols (nt = wave).
__global__ __launch_bounds__(256) void msg_kernel(
    const float* __restrict__ h, const float* __restrict__ ea,
    const float* __restrict__ fb, const _Float16* __restrict__ w2,
    const int* __restrict__ edge_index, float* __restrict__ agg) {
  __shared__ _Float16 sOut[64][72];    // 9 KB
  const int tid = threadIdx.x;
  const int wave = tid >> 6, lane = tid & 63;
  const int m15 = lane & 15, quad = lane >> 4;
  const int eb = blockIdx.x * 64;
  {  // stage out[src] as fp16 for 64 edges
    int r = tid >> 2, c0 = (tid & 3) * 16;
    int srcn = edge_index[eb + r];
#pragma unroll
    for (int c = c0; c < c0 + 16; c += 4) {
      float4 v = *(const float4*)&h[srcn * D + c];
      sOut[r][c]     = (_Float16)v.x;
      sOut[r][c + 1] = (_Float16)v.y;
      sOut[r][c + 2] = (_Float16)v.z;
      sOut[r][c + 3] = (_Float16)v.w;
    }
  }
  // edge hidden (fp32 compute, fp16 store) for 4 edges/lane: e = eb + r*16 + m15
  h8 hid0[4], hid1[4];
#pragma unroll
  for (int r = 0; r < 4; r++) {
    int e = eb + r * 16 + m15;
    float eav[6];
#pragma unroll
    for (int j = 0; j < 6; j++) eav[j] = ea[e * 6 + j];
#pragma unroll
    for (int j = 0; j < 8; j++) {
      int k0 = quad * 8 + j, k1 = 32 + quad * 8 + j;
      float a0 = fb[640 + k0], a1 = fb[640 + k1];
#pragma unroll
      for (int jj = 0; jj < 6; jj++) {
        a0 += eav[jj] * fb[256 + k0 * 6 + jj];
        a1 += eav[jj] * fb[256 + k1 * 6 + jj];
      }
      hid0[r][j] = (_Float16)fmaxf(a0, 0.f);
      hid1[r][j] = (_Float16)fmaxf(a1, 0.f);
    }
  }
  __syncthreads();
  // per-lane B fragment pointers (L2-resident, coalesced dwordx4 per lane)
  const _Float16* bp0 = w2 + (quad * 64 + wave * 16 + m15) * 8;        // kc = quad
  const _Float16* bp1 = w2 + ((4 + quad) * 64 + wave * 16 + m15) * 8;  // kc = 4+quad
  f4 zz = {0.f, 0.f, 0.f, 0.f};
  f4 acc[4];
#pragma unroll
  for (int r = 0; r < 4; r++) acc[r] = zz;
  h8 c0[4], c1[4];
#pragma unroll
  for (int t = 0; t < 4; t++) {
    c0[t] = *(const h8*)(bp0 + t * 4096);
    c1[t] = *(const h8*)(bp1 + t * 4096);
  }
#pragma unroll
  for (int p = 0; p < 16; p++) {
    h8 n0[4], n1[4];
    if (p < 15) {
#pragma unroll
      for (int t = 0; t < 4; t++) {
        int i = (p + 1) * 4 + t;
        n0[t] = *(const h8*)(bp0 + i * 4096);
        n1[t] = *(const h8*)(bp1 + i * 4096);
      }
    }
#pragma unroll
    for (int r = 0; r < 4; r++) {
      h4 os4 = *(const h4*)&sOut[r * 16 + m15][p * 4];
#pragma unroll
      for (int t = 0; t < 4; t++) {
        h8 os = splat16(os4[t]);
        acc[r] = mfma16h(hid0[r] * os, c0[t], acc[r]);
        acc[r] = mfma16h(hid1[r] * os, c1[t], acc[r]);
      }
    }
    if (p < 15) {
#pragma unroll
      for (int t = 0; t < 4; t++) { c0[t] = n0[t]; c1[t] = n1[t]; }
    }
  }
  {  // bias tail (tile 64): z = out_src
    h8 b0 = *(const h8*)(bp0 + 64 * 4096);
    h8 b1 = *(const h8*)(bp1 + 64 * 4096);
#pragma unroll
    for (int r = 0; r < 4; r++) {
      h8 a0 = *(const h8*)&sOut[r * 16 + m15][quad * 8];
      h8 a1 = *(const h8*)&sOut[r * 16 + m15][32 + quad * 8];
      acc[r] = mfma16h(a0, b0, acc[r]);
      acc[r] = mfma16h(a1, b1, acc[r]);
    }
  }
#pragma unroll
  for (int r = 0; r < 4; r++) {
#pragma unroll
    for (int reg = 0; reg < 4; reg++) {
      int ee = eb + r * 16 + quad * 4 + reg;
      int dn = edge_index[NEDGE + ee];
      atomicAdd(agg + dn * D + wave * 16 + m15, acc[r][reg]);
    }
  }
}

// ---------------- node update, fp16 MFMA; zeroes agg for the next iteration ----
__global__ __launch_bounds__(256) void update_kernel(
    float* __restrict__ h, float* __restrict__ agg, const float* __restrict__ deg,
    const _Float16* __restrict__ rtH, const _Float16* __restrict__ whhH,
    const _Float16* __restrict__ wihH, const float* __restrict__ fb) {
  __shared__ float buf[64][68];  // sH, then (after barrier) sM
  const int tid = threadIdx.x;
  const int wave = tid >> 6, lane = tid & 63;
  const int m15 = lane & 15, quad = lane >> 4;
  const int nb = blockIdx.x * 64;
  {
    int r = tid >> 2, c0 = (tid & 3) * 16;
#pragma unroll
    for (int c = c0; c < c0 + 16; c += 4)
      *(float4*)&buf[r][c] = *(const float4*)&h[(nb + r) * D + c];
  }
  __syncthreads();
  const int mrow = wave * 16 + m15;
  h8 a0, a1;
#pragma unroll
  for (int j = 0; j < 8; j++) {
    a0[j] = (_Float16)buf[mrow][quad * 8 + j];
    a1[j] = (_Float16)buf[mrow][32 + quad * 8 + j];
  }
  f4 zz = {0.f, 0.f, 0.f, 0.f};
  f4 acc[16];
#pragma unroll
  for (int nt = 0; nt < 16; nt++) acc[nt] = zz;
#pragma unroll
  for (int nt = 0; nt < 16; nt++) {
    int nn = nt * 16 + m15;
    const _Float16* bp = (nt < 4) ? (rtH + nn * D) : (whhH + (nn - 64) * D);
    h8 bh0 = *(const h8*)(bp + quad * 8);
    h8 bh1 = *(const h8*)(bp + 32 + quad * 8);
    f4 a = acc[nt];
    a = mfma16h(a0, bh0, a);
    a = mfma16h(a1, bh1, a);
    acc[nt] = a;
  }
  __syncthreads();  // everyone done reading sH
  // m = relu(root + agg/deg + conv_b), fp32, into buf; zero agg behind us
#pragma unroll
  for (int nt = 0; nt < 4; nt++) {
#pragma unroll
    for (int reg = 0; reg < 4; reg++) {
      int nloc = wave * 16 + quad * 4 + reg;
      int o = nt * 16 + m15;
      float dg = fmaxf(deg[nb + nloc], 1.f);
      int aidx = (nb + nloc) * D + o;
      float v = acc[nt][reg] + agg[aidx] / dg + fb[704 + o];
      agg[aidx] = 0.f;
      buf[nloc][o] = fmaxf(v, 0.f);
    }
  }
  __syncthreads();
  h8 m0, m1;
#pragma unroll
  for (int j = 0; j < 8; j++) {
    m0[j] = (_Float16)buf[mrow][quad * 8 + j];
    m1[j] = (_Float16)buf[mrow][32 + quad * 8 + j];
  }
  f4 g2[12];
#pragma unroll
  for (int nt = 0; nt < 12; nt++) g2[nt] = zz;
#pragma unroll
  for (int nt = 0; nt < 12; nt++) {
    int nn = nt * 16 + m15;
    const _Float16* bp = wihH + nn * D;
    h8 bh0 = *(const h8*)(bp + quad * 8);
    h8 bh1 = *(const h8*)(bp + 32 + quad * 8);
    f4 a = g2[nt];
    a = mfma16h(m0, bh0, a);
    a = mfma16h(m1, bh1, a);
    g2[nt] = a;
  }
#pragma unroll
  for (int nt = 0; nt < 4; nt++) {
#pragma unroll
    for (int reg = 0; reg < 4; reg++) {
      int nloc = wave * 16 + quad * 4 + reg;
      int o = nt * 16 + m15;
      int gidx = (nb + nloc) * D + o;
      float gir = g2[nt][reg]      + fb[768 + o];
      float giz = g2[nt + 4][reg]  + fb[768 + 64 + o];
      float gin = g2[nt + 8][reg]  + fb[768 + 128 + o];
      float ghr = acc[nt + 4][reg]  + fb[960 + o];
      float ghz = acc[nt + 8][reg]  + fb[960 + 64 + o];
      float ghn = acc[nt + 12][reg] + fb[960 + 128 + o];
      float rr = sigm(gir + ghr);
      float zg = sigm(giz + ghz);
      float nnv = tanhf(gin + rr * ghn);
      float hv = h[gidx];
      h[gidx] = (1.f - zg) * nnv + zg * hv;
    }
  }
}

// ---------------- fused Set2Set (6 steps) + memory LSTM; wih in registers ----
__global__ __launch_bounds__(256) void s2s_kernel(
    const float* __restrict__ h,
    const float* __restrict__ wihT, const float* __restrict__ whhT,
    const float* __restrict__ mwihT, const float* __restrict__ fb,
    float* __restrict__ hx_f32, float* __restrict__ dout) {
  __shared__ float outL[64][65];
  __shared__ float qs[128];
  __shared__ float hsv[64], csv[64], sg[256], sa[64];
  __shared__ float spart[4][64];
  const int t = threadIdx.x;
  const int g = blockIdx.x;
  float wr[128];
#pragma unroll
  for (int j = 0; j < 128; j++) wr[j] = wihT[j * 256 + t];
  for (int idx = t; idx < 64 * 64; idx += 256) outL[idx >> 6][idx & 63] = h[g * 4096 + idx];
  if (t < 128) qs[t] = 0.f;
  if (t < 64) { hsv[t] = 0.f; csv[t] = 0.f; }
  __syncthreads();
  for (int step = 0; step < 6; step++) {
    float acc = fb[1152 + t] + fb[1408 + t];
#pragma unroll
    for (int j = 0; j < 128; j++) acc += qs[j] * wr[j];
#pragma unroll 8
    for (int j = 0; j < 64; j++) acc += hsv[j] * whhT[j * 256 + t];
    sg[t] = acc;
    __syncthreads();
    if (t < 64) {
      float cn = sigm(sg[64 + t]) * csv[t] + sigm(sg[t]) * tanhf(sg[128 + t]);
      csv[t] = cn;
      hsv[t] = sigm(sg[192 + t]) * tanhf(cn);
    }
    __syncthreads();
    if (t < 64) {
      float e = 0.f;
      for (int d2 = 0; d2 < 64; d2++) e += outL[t][d2] * hsv[d2];
      float mx = e;
      for (int off = 32; off > 0; off >>= 1) mx = fmaxf(mx, __shfl_xor(mx, off));
      float a = __expf(e - mx);
      float s = a;
      for (int off = 32; off > 0; off >>= 1) s += __shfl_xor(s, off);
      sa[t] = a / s;
    }
    __syncthreads();
    {
      int o = t & 63, part = t >> 6;
      float r = 0.f;
      for (int n2 = part * 16; n2 < part * 16 + 16; n2++) r += sa[n2] * outL[n2][o];
      spart[part][o] = r;
    }
    __syncthreads();
    if (t < 64) {
      qs[t] = hsv[t];
      qs[64 + t] = spart[0][t] + spart[1][t] + spart[2][t] + spart[3][t];
    }
    __syncthreads();
  }
  float acc = fb[1664 + t] + fb[1920 + t];
#pragma unroll 8
  for (int j = 0; j < 128; j++) acc += qs[j] * mwihT[j * 256 + t];
  sg[t] = acc;
  __syncthreads();
  if (t < 64) {
    float cn = sigm(sg[t]) * tanhf(sg[128 + t]);
    float hn = sigm(sg[192 + t]) * tanhf(cn);
    hx_f32[g * 64 + t] = hn;
    dout[TTOT * 6 + g * 64 + t] = hn;
    dout[TTOT * 6 + NG * 64 + g * 64 + t] = cn;
  }
}

// ---------------- head: faithful permute/reshape + lin1 + lin2; transposed l1w ----
__global__ __launch_bounds__(64) void head_kernel(
    const float* __restrict__ h, const float* __restrict__ hx_f32,
    const int* __restrict__ nonring, const int* __restrict__ nrbidx,
    const float* __restrict__ l1wT, const float* __restrict__ l2w,
    const float* __restrict__ fb, float* __restrict__ dout) {
  __shared__ float feat[320];
  __shared__ float so1[64];
  const int r = blockIdx.x;
  const int lane = threadIdx.x;
  const int blk = r % 48, di = r / 48;
  const int tt = blk * 64 + lane;
  feat[lane * 5] = hx_f32[nrbidx[tt] * 64 + di];
#pragma unroll
  for (int s = 1; s <= 4; s++)
    feat[lane * 5 + s] = h[nonring[(s - 1) * TTOT + tt] * 64 + di];
  __syncthreads();
  float acc = fb[2176 + lane];
#pragma unroll 8
  for (int c = 0; c < 320; c++) acc += feat[c] * l1wT[c * 64 + lane];
  so1[lane] = fmaxf(acc, 0.f);
  __syncthreads();
  if (lane < 6) {
    float a2 = fb[2240 + lane];
    for (int j = 0; j < 64; j++) a2 += so1[j] * l2w[lane * 64 + j];
    dout[r * 6 + lane] = a2;
  }
}

extern "C" void kernel_launch(void* const* d_in, const int* in_sizes, int n_in,
                              void* d_out, int out_size, void* d_ws, size_t ws_size,
                              hipStream_t stream) {
  (void)in_sizes; (void)n_in; (void)out_size;
  const float* x         = (const float*)d_in[0];
  const float* edge_attr = (const float*)d_in[1];
  const int* edge_index  = (const int*)d_in[2];
  const int* nonring     = (const int*)d_in[4];
  const int* nrbidx      = (const int*)d_in[5];
  float* out = (float*)d_out;

  char* ws = (char*)d_ws;
  float*    h      = (float*)(ws + WS_H);
  float*    agg    = (float*)(ws + WS_AGG);
  _Float16* w2     = (_Float16*)(ws + WS_W2);
  _Float16* rtH    = (_Float16*)(ws + WS_RT);
  _Float16* whhH   = (_Float16*)(ws + WS_WHH);
  _Float16* wihH   = (_Float16*)(ws + WS_WIH);
  float*    swihT  = (float*)(ws + WS_SWIHT);
  float*    swhhT  = (float*)(ws + WS_SWHHT);
  float*    mwihT  = (float*)(ws + WS_MWIHT);
  float*    l1wT   = (float*)(ws + WS_L1WT);
  float*    l2wF   = (float*)(ws + WS_L2WF);
  float*    fb     = (float*)(ws + WS_FB);
  float*    deg    = (float*)(ws + WS_DEG);
  float*    hx_f32 = (float*)(ws + WS_HX);
  if (ws_size < (size_t)WS_NEED) return;

  Srcs S;
  S.p[0] = d_in[8];   S.p[1] = d_in[9];   S.p[2] = d_in[10];  S.p[3] = d_in[11];
  S.p[4] = d_in[12];  S.p[5] = d_in[13];  S.p[6] = d_in[14];  S.p[7] = d_in[15];
  S.p[8] = d_in[16];  S.p[9] = d_in[17];  S.p[10] = d_in[18]; S.p[11] = d_in[19];
  S.p[12] = d_in[20]; S.p[13] = d_in[21]; S.p[14] = d_in[22]; S.p[15] = d_in[23];
  S.p[16] = d_in[24]; S.p[17] = d_in[26]; S.p[18] = d_in[27]; S.p[19] = d_in[28];
  S.p[20] = d_in[29]; S.p[21] = d_in[30]; S.p[22] = d_in[31];
  pack_kernel<<<(399942 + 255) / 256, 256, 0, stream>>>(S, ws);

  init_kernel<<<NNODE * D / 256, 256, 0, stream>>>(x, fb, h);
  hipMemsetAsync(deg, 0, NNODE * 4, stream);
  hipMemsetAsync(agg, 0, NNODE * D * 4, stream);
  deg_kernel<<<NEDGE / 256, 256, 0, stream>>>(edge_index, deg);

  for (int it = 0; it < 6; it++) {
    msg_kernel<<<NEDGE / 64, 256, 0, stream>>>(h, edge_attr, fb, w2, edge_index, agg);
    update_kernel<<<NNODE / 64, 256, 0, stream>>>(h, agg, deg, rtH, whhH, wihH, fb);
  }

  s2s_kernel<<<NG, 256, 0, stream>>>(h, swihT, swhhT, mwihT, fb, hx_f32, out);
  head_kernel<<<TTOT, 64, 0, stream>>>(h, hx_f32, nonring, nrbidx, l1wT, l2wF, fb, out);
}